// Round 2
// baseline (320.691 us; speedup 1.0000x reference)
//
#include <hip/hip_runtime.h>
#include <stdint.h>

// B=4, S=2048, D_IN=D_MODEL=1024.
// Pipeline: absmax(W) -> quantize W^T bf16 -> cast q,k,v bf16 ->
//   merged proj GEMM (256^2 8-phase schedule; z<2 emits qp/kp fp8-e4m3,
//   z==2 stores vp^T bf16)
//   -> QK^T via MX-scaled fp8 MFMA (K=128, scale=1) -> softmax(bf16) -> PV bf16.
// fp8 is used ONLY where softmax averaging attenuates the noise (qp/kp);
// vp and P stay bf16 (their error enters the output unattenuated).

typedef unsigned short ushort_t;
typedef __attribute__((ext_vector_type(8))) short short8;
typedef __bf16 bf16x8 __attribute__((ext_vector_type(8)));
typedef __attribute__((ext_vector_type(4))) float floatx4;
typedef __attribute__((ext_vector_type(8))) int int8v;

__device__ __forceinline__ ushort_t f2bf(float x) {
  unsigned u = __float_as_uint(x);
  unsigned r = (u + 0x7fffu + ((u >> 16) & 1u)) >> 16;  // RNE
  return (ushort_t)r;
}
__device__ __forceinline__ float bf2f(ushort_t u) {
  return __uint_as_float(((unsigned)u) << 16);
}
__device__ __forceinline__ unsigned char f2fp8(float x) {
  // v_cvt_pk_fp8_f32 (RNE, saturating), take low byte
  return (unsigned char)(__builtin_amdgcn_cvt_pk_fp8_f32(x, x, 0, false) & 0xff);
}

__device__ __forceinline__ void gl_lds16(const void* g, void* l) {
  __builtin_amdgcn_global_load_lds(
      (const __attribute__((address_space(1))) unsigned int*)g,
      (__attribute__((address_space(3))) unsigned int*)l, 16, 0, 0);
}

// ---------------------------------------------------------------------------
// Proj GEMM: 256x256 tile, BK=64, 8 waves (2M x 4N), 8-phase schedule with
// counted vmcnt (T3+T4) + setprio (T5). K=1024 hardcoded (16 K-tiles).
// LDS: 2 dbuf x 256x64 bf16 per matrix = 128 KiB total -> 1 block/CU.
// Phase p computes C-quadrant (qm,qn) of this K-tile: 16 MFMA.
// Fragment register reuse: A(qm) read once, reused across qn; B(qn0/qn1)
// both kept, so each LDS half's LAST read is >=1 barrier before its restage.
// Staging per phase = 1 half-tile = 2 x global_load_lds_dwordx4 per wave.
// vmcnt(6) (=3 half-tiles in flight) only at phases 4/8; vmcnt(0) only in
// the epilogue iteration.
// ---------------------------------------------------------------------------

#define BARRIER()                        \
  {                                      \
    __builtin_amdgcn_sched_barrier(0);   \
    __builtin_amdgcn_s_barrier();        \
    __builtin_amdgcn_sched_barrier(0);   \
  }
#define WAIT_LGKM0()                                  \
  {                                                   \
    asm volatile("s_waitcnt lgkmcnt(0)" ::: "memory"); \
    __builtin_amdgcn_sched_barrier(0);                \
  }
#define WAIT_VM(n)                                         \
  {                                                        \
    asm volatile("s_waitcnt vmcnt(" #n ")" ::: "memory");  \
    __builtin_amdgcn_sched_barrier(0);                     \
  }

// Stage half h (128 rows) of K-tile kt of A into buf. 2 issues x 64 rows.
// gA already carries (a_row0 + crow)*1024 + schunk*8; kt adds the K offset.
#define STAGE_A(kt, h, buf)                                              \
  {                                                                      \
    gl_lds16(gA + (long)(h)*131072 + (long)(kt)*64,                      \
             sA + (buf)*16384 + ((h)*128 + wave * 8) * 64);              \
    gl_lds16(gA + (long)(h)*131072 + 65536 + (long)(kt)*64,              \
             sA + (buf)*16384 + ((h)*128 + 64 + wave * 8) * 64);         \
  }
#define STAGE_B(kt, h, buf)                                              \
  {                                                                      \
    gl_lds16(gB + (long)(h)*131072 + (long)(kt)*64,                      \
             sB + (buf)*16384 + ((h)*128 + wave * 8) * 64);              \
    gl_lds16(gB + (long)(h)*131072 + 65536 + (long)(kt)*64,              \
             sB + (buf)*16384 + ((h)*128 + 64 + wave * 8) * 64);         \
  }

#define RD_A(buf, qm)                                                     \
  {                                                                       \
    _Pragma("unroll") for (int mi = 0; mi < 4; ++mi)                      \
        _Pragma("unroll") for (int s = 0; s < 2; ++s) aT[mi][s] =         \
            *(const bf16x8*)&sA[(buf)*16384 + (qm)*8192 + offA[mi][s]];   \
  }
#define RD_B(dst, buf, qn)                                                \
  {                                                                       \
    _Pragma("unroll") for (int ni = 0; ni < 2; ++ni)                      \
        _Pragma("unroll") for (int s = 0; s < 2; ++s) dst[ni][s] =        \
            *(const bf16x8*)&sB[(buf)*16384 + (qn)*8192 + offB[ni][s]];   \
  }
#define MM(qm, qn, BR)                                                       \
  {                                                                          \
    __builtin_amdgcn_s_setprio(1);                                           \
    _Pragma("unroll") for (int s = 0; s < 2; ++s)                            \
        _Pragma("unroll") for (int mi = 0; mi < 4; ++mi)                     \
            _Pragma("unroll") for (int ni = 0; ni < 2; ++ni) acc[qm][qn][mi] \
                [ni] = __builtin_amdgcn_mfma_f32_16x16x32_bf16(              \
                    aT[mi][s], BR[ni][s], acc[qm][qn][mi][ni], 0, 0, 0);     \
    __builtin_amdgcn_s_setprio(0);                                           \
  }

__global__ __launch_bounds__(512, 2) void gemm256_proj(
    const ushort_t* __restrict__ A, const ushort_t* __restrict__ Bt,
    void* __restrict__ Cv, void* __restrict__ Cv8,
    const float* __restrict__ bias0, const float* __restrict__ bias1,
    const float* __restrict__ bias2) {
  __shared__ __attribute__((aligned(16))) ushort_t sA[2 * 256 * 64];
  __shared__ __attribute__((aligned(16))) ushort_t sB[2 * 256 * 64];

  const int t = threadIdx.x;
  const int lane = t & 63;
  const int wave = t >> 6;   // 0..7
  const int wm = wave >> 2;  // 0..1
  const int wn = wave & 3;   // 0..3
  const int bm = blockIdx.x; // 0..31 (bm-fastest: bn-sharers land on same XCD)
  const int bn = blockIdx.y; // 0..3
  const int bz = blockIdx.z; // 0..2

  const ushort_t* Ab = A + (long)bz * 8388608L;   // 8192*1024
  const ushort_t* Bb = Bt + (long)bz * 1048576L;  // 1024*1024

  const long a_row0 = (long)bm * 256;
  const long b_row0 = (long)bn * 256;

  // Staging geometry: 64 rows x 8 chunks(16B) per issue (512 thr x 16B).
  // XOR swizzle: LDS[row][chunk] holds global[row][chunk ^ (row&7)].
  const int crow = t >> 3;                  // 0..63
  const int schunk = (t & 7) ^ (crow & 7);  // swizzled global chunk
  const ushort_t* gA = Ab + (a_row0 + crow) * 1024 + schunk * 8;
  const ushort_t* gB = Bb + (b_row0 + crow) * 1024 + schunk * 8;

  floatx4 acc[2][2][4][2];
#pragma unroll
  for (int a = 0; a < 2; ++a)
#pragma unroll
    for (int b = 0; b < 2; ++b)
#pragma unroll
      for (int c = 0; c < 4; ++c)
#pragma unroll
        for (int d = 0; d < 2; ++d) acc[a][b][c][d] = {0.f, 0.f, 0.f, 0.f};

  const int fr = lane & 15;
  const int fg = lane >> 4;  // 0..3: which 16B chunk within a 32-k step

  int offA[4][2], offB[2][2];
#pragma unroll
  for (int mi = 0; mi < 4; ++mi) {
    int rowA = wm * 64 + mi * 16 + fr;
#pragma unroll
    for (int s = 0; s < 2; ++s)
      offA[mi][s] = rowA * 64 + (((s * 4 + fg) ^ (rowA & 7)) * 8);
  }
#pragma unroll
  for (int ni = 0; ni < 2; ++ni) {
    int rowB = wn * 32 + ni * 16 + fr;
#pragma unroll
    for (int s = 0; s < 2; ++s)
      offB[ni][s] = rowB * 64 + (((s * 4 + fg) ^ (rowB & 7)) * 8);
  }

  bf16x8 aT[4][2], bT0[2][2], bT1[2][2];

  // Prologue: tile0 full + {A0,B0,B1} of tile1; A1(1) staged in loop Ph1.
  STAGE_A(0, 0, 0);
  STAGE_A(0, 1, 0);
  STAGE_B(0, 0, 0);
  STAGE_B(0, 1, 0);
  STAGE_A(1, 0, 1);
  STAGE_B(1, 0, 1);
  STAGE_B(1, 1, 1);
  WAIT_VM(6);  // 14 loads issued; tile0 (oldest 8) complete
  BARRIER();

#pragma unroll 1
  for (int i = 0; i < 7; ++i) {
    const int t0 = 2 * i;  // tiles t0 (buf0), t0+1 (buf1)
    // Phase 1: quadrant (0,0) of tile t0
    RD_A(0, 0);
    RD_B(bT0, 0, 0);
    STAGE_A(t0 + 1, 1, 1);  // A1(t0+1); slot last read prev-iter Ph7
    BARRIER();
    WAIT_LGKM0();
    MM(0, 0, bT0);
    BARRIER();
    // Phase 2: (0,1)
    RD_B(bT1, 0, 1);
    STAGE_A(t0 + 2, 0, 0);  // A0 slot last read Ph1
    BARRIER();
    WAIT_LGKM0();
    MM(0, 1, bT1);
    BARRIER();
    // Phase 3: (1,0)  (bT0 held in regs since Ph1)
    RD_A(0, 1);
    STAGE_B(t0 + 2, 0, 0);  // B0 slot last read Ph1
    BARRIER();
    WAIT_LGKM0();
    MM(1, 0, bT0);
    BARRIER();
    // Phase 4: (1,1)  (no new ds_reads)
    STAGE_B(t0 + 2, 1, 0);  // B1 slot last read Ph2
    BARRIER();
    WAIT_LGKM0();
    MM(1, 1, bT1);
    WAIT_VM(6);  // tile t0+1 halves complete; 3 halves of t0+2 in flight
    BARRIER();
    // Phase 5: (0,0) of tile t0+1
    RD_A(1, 0);
    RD_B(bT0, 1, 0);
    STAGE_A(t0 + 2, 1, 0);  // A1 slot last read Ph3
    BARRIER();
    WAIT_LGKM0();
    MM(0, 0, bT0);
    BARRIER();
    // Phase 6: (0,1)
    RD_B(bT1, 1, 1);
    STAGE_A(t0 + 3, 0, 1);
    BARRIER();
    WAIT_LGKM0();
    MM(0, 1, bT1);
    BARRIER();
    // Phase 7: (1,0)
    RD_A(1, 1);
    STAGE_B(t0 + 3, 0, 1);
    BARRIER();
    WAIT_LGKM0();
    MM(1, 0, bT0);
    BARRIER();
    // Phase 8: (1,1)
    STAGE_B(t0 + 3, 1, 1);
    BARRIER();
    WAIT_LGKM0();
    MM(1, 1, bT1);
    WAIT_VM(6);  // tile t0+2 complete; 3 halves of t0+3 in flight
    BARRIER();
  }

  // Epilogue: tiles 14 (buf0), 15 (buf1)
  RD_A(0, 0);
  RD_B(bT0, 0, 0);
  STAGE_A(15, 1, 1);  // last half
  BARRIER();
  WAIT_LGKM0();
  MM(0, 0, bT0);
  BARRIER();
  RD_B(bT1, 0, 1);
  BARRIER();
  WAIT_LGKM0();
  MM(0, 1, bT1);
  BARRIER();
  RD_A(0, 1);
  BARRIER();
  WAIT_LGKM0();
  MM(1, 0, bT0);
  BARRIER();
  BARRIER();
  WAIT_LGKM0();
  MM(1, 1, bT1);
  WAIT_VM(0);  // drain: tile 15 fully staged
  BARRIER();
  RD_A(1, 0);
  RD_B(bT0, 1, 0);
  BARRIER();
  WAIT_LGKM0();
  MM(0, 0, bT0);
  BARRIER();
  RD_B(bT1, 1, 1);
  BARRIER();
  WAIT_LGKM0();
  MM(0, 1, bT1);
  BARRIER();
  RD_A(1, 1);
  BARRIER();
  WAIT_LGKM0();
  MM(1, 0, bT0);
  BARRIER();
  WAIT_LGKM0();
  MM(1, 1, bT1);

  // C/D layout: row=(lane>>4)*4+reg, col=lane&15  [m89/m91]
  const int r0v = fg * 4;
  const float* bias = (bz == 0) ? bias0 : (bz == 1 ? bias1 : bias2);
  unsigned char* C8 = (unsigned char*)Cv8 + (long)bz * 8388608L;
  ushort_t* CvpT = (ushort_t*)Cv;

#pragma unroll
  for (int qm = 0; qm < 2; ++qm)
#pragma unroll
    for (int qn = 0; qn < 2; ++qn)
#pragma unroll
      for (int mi = 0; mi < 4; ++mi)
#pragma unroll
        for (int ni = 0; ni < 2; ++ni) {
          long gm0 = a_row0 + qm * 128 + wm * 64 + mi * 16 + r0v;
          long gn = b_row0 + qn * 128 + wn * 32 + ni * 16 + fr;
          float vv[4];
#pragma unroll
          for (int r = 0; r < 4; ++r)
            vv[r] = acc[qm][qn][mi][ni][r] + bias[gn];
          if (bz == 2) {
            // vp^T[b][gn][s]: r=0..3 contiguous in s; 8B packed store
            long b = gm0 >> 11, s = gm0 & 2047;
            ushort4 u4;
            u4.x = f2bf(vv[0]);
            u4.y = f2bf(vv[1]);
            u4.z = f2bf(vv[2]);
            u4.w = f2bf(vv[3]);
            *(ushort4*)&CvpT[b * (2048L * 1024L) + gn * 2048L + s] = u4;
          } else {
            // fp8 e4m3 store: qp8/kp8 [8192][1024] row-major
#pragma unroll
            for (int r = 0; r < 4; ++r) C8[(gm0 + r) * 1024 + gn] = f2fp8(vv[r]);
          }
        }
}

#define BM 128
#define BN 128
#define BK 64

// CMODE: 2 = fp32 store Cz[gm*ldc+gn]  (PV GEMM)
// SWAP:  1 = bm from blockIdx.x (bm-fastest for XCD A-stripe sharing)
template <int CMODE, int SWAP>
__global__ __launch_bounds__(256, 2) void gemm_bt(
    const ushort_t* __restrict__ A, const ushort_t* __restrict__ Bt,
    void* __restrict__ Cv, void* __restrict__ Cv8,
    const float* __restrict__ bias0, const float* __restrict__ bias1,
    const float* __restrict__ bias2, int K, int ldc, float alpha, long strideA,
    long strideB, long strideC) {
  __shared__ __attribute__((aligned(16))) ushort_t sA[BM * BK];
  __shared__ __attribute__((aligned(16))) ushort_t sB[BN * BK];

  const int t = threadIdx.x;
  const int lane = t & 63;
  const int wave = t >> 6;
  const int bm = SWAP ? blockIdx.x : blockIdx.y;
  const int bn = SWAP ? blockIdx.y : blockIdx.x;
  const int bz = blockIdx.z;

  const ushort_t* Ab = A + (long)bz * strideA;
  const ushort_t* Bb = Bt + (long)bz * strideB;

  const long a_row0 = (long)bm * BM;
  const long b_row0 = (long)bn * BN;

  // Staging: 32 rows x 8 chunks(16B) per issue; 4 issues per matrix.
  // XOR swizzle: LDS[row][chunk] holds global[row][chunk ^ (row&7)].
  const int crow = t >> 3;                  // 0..31
  const int schunk = (t & 7) ^ (crow & 7);  // swizzled global chunk

  const ushort_t* gA = Ab + (a_row0 + crow) * (long)K + schunk * 8;
  const ushort_t* gB = Bb + (b_row0 + crow) * (long)K + schunk * 8;

  ushort_t* lA = sA + wave * 512;  // + issue*2048; HW adds lane*16B
  ushort_t* lB = sB + wave * 512;

  floatx4 acc[4][4];
#pragma unroll
  for (int i = 0; i < 4; ++i)
#pragma unroll
    for (int j = 0; j < 4; ++j) acc[i][j] = {0.f, 0.f, 0.f, 0.f};

  const int wm = (wave & 1) * 64;
  const int wn = (wave >> 1) * 64;
  const int fr = lane & 15;
  const int fg = lane >> 4;  // 0..3: which 16B chunk within a 32-k step

  int offA[2][4], offB[2][4];
#pragma unroll
  for (int s = 0; s < 2; ++s)
#pragma unroll
    for (int i = 0; i < 4; ++i) {
      int rowA = wm + i * 16 + fr;
      int rowB = wn + i * 16 + fr;
      int cg = s * 4 + fg;
      offA[s][i] = rowA * BK + ((cg ^ (rowA & 7)) * 8);
      offB[s][i] = rowB * BK + ((cg ^ (rowB & 7)) * 8);
    }

  for (int k0 = 0; k0 < K; k0 += BK) {
#pragma unroll
    for (int i = 0; i < 4; ++i) {
      gl_lds16(gA + (long)i * 32 * K, lA + i * 2048);
      gl_lds16(gB + (long)i * 32 * K, lB + i * 2048);
    }
    gA += BK;
    gB += BK;
    __syncthreads();  // staging complete

#pragma unroll
    for (int s = 0; s < 2; ++s) {
      bf16x8 af[4], bfr[4];
#pragma unroll
      for (int i = 0; i < 4; ++i) {
        af[i] = *(const bf16x8*)&sA[offA[s][i]];
        bfr[i] = *(const bf16x8*)&sB[offB[s][i]];
      }
#pragma unroll
      for (int mi = 0; mi < 4; ++mi)
#pragma unroll
        for (int ni = 0; ni < 4; ++ni)
          acc[mi][ni] = __builtin_amdgcn_mfma_f32_16x16x32_bf16(
              af[mi], bfr[ni], acc[mi][ni], 0, 0, 0);
    }
    __syncthreads();  // reads done before next stage overwrites
  }

  // C/D layout: row=(lane>>4)*4+reg, col=lane&15  [m89/m91]
  const int r0 = fg * 4;
  const int cc = fr;
  float* Cz32 = (float*)Cv + (long)bz * strideC;

#pragma unroll
  for (int mi = 0; mi < 4; ++mi) {
#pragma unroll
    for (int ni = 0; ni < 4; ++ni) {
      long gm0 = a_row0 + wm + mi * 16 + r0;
      long gn = b_row0 + wn + ni * 16 + cc;
      float vv[4];
#pragma unroll
      for (int r = 0; r < 4; ++r) vv[r] = acc[mi][ni][r] * alpha;
      if (CMODE == 2) {
#pragma unroll
        for (int r = 0; r < 4; ++r) Cz32[(gm0 + r) * ldc + gn] = vv[r];
      }
    }
  }
}

// QK^T with MX-scaled fp8 MFMA: K=128/instr, scale=2^0 (E8M0 127).
// A=qp8, B=kp8, both [4][2048][1024] fp8 e4m3; P bf16 [4][2048][2048], /32.
__global__ __launch_bounds__(256, 2) void qk_fp8(
    const unsigned char* __restrict__ Q8, const unsigned char* __restrict__ K8,
    ushort_t* __restrict__ P) {
  __shared__ __attribute__((aligned(16))) unsigned char sA[128 * 128];
  __shared__ __attribute__((aligned(16))) unsigned char sB[128 * 128];
  const int t = threadIdx.x;
  const int lane = t & 63, wave = t >> 6;
  const int bm = blockIdx.x, bn = blockIdx.y, bz = blockIdx.z;

  const unsigned char* Ab = Q8 + (long)bz * 2097152L + (long)bm * 128 * 1024;
  const unsigned char* Bb = K8 + (long)bz * 2097152L + (long)bn * 128 * 1024;

  // Staging: row = 128 B (BK=128 fp8). 256 thr x 16B = 32 rows/issue, 4 issues.
  const int crow = t >> 3;
  const int schunk = (t & 7) ^ (crow & 7);
  const unsigned char* gA = Ab + crow * 1024 + schunk * 16;
  const unsigned char* gB = Bb + crow * 1024 + schunk * 16;
  unsigned char* lA = sA + wave * 1024;  // + issue*4096; HW adds lane*16B
  unsigned char* lB = sB + wave * 1024;

  floatx4 acc[4][4];
#pragma unroll
  for (int i = 0; i < 4; ++i)
#pragma unroll
    for (int j = 0; j < 4; ++j) acc[i][j] = {0.f, 0.f, 0.f, 0.f};

  const int wm = (wave & 1) * 64;
  const int wn = (wave >> 1) * 64;
  const int fr = lane & 15;
  const int fg = lane >> 4;  // quad: k-bytes [fg*32, fg*32+32)

  int offA[4][2], offB[4][2];
#pragma unroll
  for (int i = 0; i < 4; ++i) {
    int rA = wm + i * 16 + fr;
    int rB = wn + i * 16 + fr;
    offA[i][0] = rA * 128 + (((2 * fg) ^ (rA & 7)) * 16);
    offA[i][1] = rA * 128 + (((2 * fg + 1) ^ (rA & 7)) * 16);
    offB[i][0] = rB * 128 + (((2 * fg) ^ (rB & 7)) * 16);
    offB[i][1] = rB * 128 + (((2 * fg + 1) ^ (rB & 7)) * 16);
  }

  for (int k0 = 0; k0 < 1024; k0 += 128) {
#pragma unroll
    for (int i = 0; i < 4; ++i) {
      gl_lds16(gA + (long)i * 32 * 1024, lA + i * 4096);
      gl_lds16(gB + (long)i * 32 * 1024, lB + i * 4096);
    }
    gA += 128;
    gB += 128;
    __syncthreads();

    int8v af[4], bfr[4];
#pragma unroll
    for (int i = 0; i < 4; ++i) {
      int4 lo = *(const int4*)&sA[offA[i][0]];
      int4 hi = *(const int4*)&sA[offA[i][1]];
      af[i][0] = lo.x; af[i][1] = lo.y; af[i][2] = lo.z; af[i][3] = lo.w;
      af[i][4] = hi.x; af[i][5] = hi.y; af[i][6] = hi.z; af[i][7] = hi.w;
      int4 lo2 = *(const int4*)&sB[offB[i][0]];
      int4 hi2 = *(const int4*)&sB[offB[i][1]];
      bfr[i][0] = lo2.x; bfr[i][1] = lo2.y; bfr[i][2] = lo2.z; bfr[i][3] = lo2.w;
      bfr[i][4] = hi2.x; bfr[i][5] = hi2.y; bfr[i][6] = hi2.z; bfr[i][7] = hi2.w;
    }
#pragma unroll
    for (int mi = 0; mi < 4; ++mi)
#pragma unroll
      for (int ni = 0; ni < 4; ++ni)
        acc[mi][ni] = __builtin_amdgcn_mfma_scale_f32_16x16x128_f8f6f4(
            af[mi], bfr[ni], acc[mi][ni], 0, 0, 0, 127, 0, 127);
    __syncthreads();
  }

  const int r0 = fg * 4;
  const int cc = fr;
#pragma unroll
  for (int mi = 0; mi < 4; ++mi)
#pragma unroll
    for (int ni = 0; ni < 4; ++ni)
#pragma unroll
      for (int r = 0; r < 4; ++r) {
        long gm = (long)bm * 128 + wm + mi * 16 + r0 + r;
        long gn = (long)bn * 128 + wn + ni * 16 + cc;
        P[(long)bz * 4194304L + gm * 2048 + gn] =
            f2bf(acc[mi][ni][r] * 0.03125f);
      }
}

__global__ __launch_bounds__(256) void absmax_k(
    const float* __restrict__ W0, const float* __restrict__ W1,
    const float* __restrict__ W2, unsigned* __restrict__ outv) {
  const float* W = blockIdx.z == 0 ? W0 : (blockIdx.z == 1 ? W1 : W2);
  float m = 0.f;
  const long n = 1024L * 1024L;
  for (long i = (long)blockIdx.x * blockDim.x + threadIdx.x; i < n;
       i += (long)gridDim.x * blockDim.x)
    m = fmaxf(m, fabsf(W[i]));
  for (int off = 32; off; off >>= 1) m = fmaxf(m, __shfl_xor(m, off));
  __shared__ float red[4];
  int lane = threadIdx.x & 63, wave = threadIdx.x >> 6;
  if (lane == 0) red[wave] = m;
  __syncthreads();
  if (threadIdx.x == 0) {
    m = fmaxf(fmaxf(red[0], red[1]), fmaxf(red[2], red[3]));
    atomicMax(&outv[blockIdx.z], __float_as_uint(m));  // positive: uint order
  }
}

__global__ __launch_bounds__(256) void quant_w_k(
    const float* __restrict__ W0, const float* __restrict__ W1,
    const float* __restrict__ W2, const unsigned* __restrict__ scales,
    ushort_t* __restrict__ Wt) {
  const int z = blockIdx.z;
  const float* W = z == 0 ? W0 : (z == 1 ? W1 : W2);
  const float s = __uint_as_float(scales[z]) * (1.0f / 128.0f);
  __shared__ float tile[32][33];
  const int tx = threadIdx.x & 31, ty = threadIdx.x >> 5;
  const int k0 = blockIdx.y * 32, n0 = blockIdx.x * 32;
#pragma unroll
  for (int i = 0; i < 4; ++i)
    tile[ty + i * 8][tx] = W[(long)(k0 + ty + i * 8) * 1024 + n0 + tx];
  __syncthreads();
  ushort_t* wt = Wt + (long)z * 1024 * 1024;
#pragma unroll
  for (int i = 0; i < 4; ++i) {
    float w = tile[tx][ty + i * 8];
    float qv = rintf(w / s) * s;  // rintf = RNE = jnp.round
    wt[(long)(n0 + ty + i * 8) * 1024 + k0 + tx] = f2bf(qv);
  }
}

__global__ __launch_bounds__(256) void cast3_k(
    const float* __restrict__ q, const float* __restrict__ k,
    const float* __restrict__ v, ushort_t* __restrict__ qb,
    ushort_t* __restrict__ kb, ushort_t* __restrict__ vb) {
  const int z = blockIdx.z;
  const float4* src = (const float4*)(z == 0 ? q : (z == 1 ? k : v));
  ushort_t* dst = z == 0 ? qb : (z == 1 ? kb : vb);
  const long nv = (4L * 2048 * 1024) / 4;
  for (long i = (long)blockIdx.x * blockDim.x + threadIdx.x; i < nv;
       i += (long)gridDim.x * blockDim.x) {
    float4 f = src[i];
    ushort4 u4;
    u4.x = f2bf(f.x); u4.y = f2bf(f.y); u4.z = f2bf(f.z); u4.w = f2bf(f.w);
    *(ushort4*)(dst + i * 4) = u4;
  }
}

__global__ __launch_bounds__(256) void softmax_k(ushort_t* __restrict__ P) {
  const long row = blockIdx.x;
  ushort_t* p = P + row * 2048;
  const int t = threadIdx.x;
  const int lane = t & 63, wave = t >> 6;
  short8 v8 = *(const short8*)&p[t * 8];
  float x[8];
#pragma unroll
  for (int j = 0; j < 8; ++j) x[j] = bf2f((ushort_t)v8[j]);
  float m = x[0];
#pragma unroll
  for (int j = 1; j < 8; ++j) m = fmaxf(m, x[j]);
  for (int off = 32; off; off >>= 1) m = fmaxf(m, __shfl_xor(m, off));
  __shared__ float rmax[4], rsum[4];
  if (lane == 0) rmax[wave] = m;
  __syncthreads();
  m = fmaxf(fmaxf(rmax[0], rmax[1]), fmaxf(rmax[2], rmax[3]));
  float s = 0.f;
#pragma unroll
  for (int j = 0; j < 8; ++j) {
    x[j] = __expf(x[j] - m);
    s += x[j];
  }
  for (int off = 32; off; off >>= 1) s += __shfl_xor(s, off);
  if (lane == 0) rsum[wave] = s;
  __syncthreads();
  s = rsum[0] + rsum[1] + rsum[2] + rsum[3];
  float inv = 1.0f / s;
  short8 o8;
#pragma unroll
  for (int j = 0; j < 8; ++j) o8[j] = (short)f2bf(x[j] * inv);
  *(short8*)&p[t * 8] = o8;
}

extern "C" void kernel_launch(void* const* d_in, const int* in_sizes, int n_in,
                              void* d_out, int out_size, void* d_ws,
                              size_t ws_size, hipStream_t stream) {
  const float* q = (const float*)d_in[0];
  const float* k = (const float*)d_in[1];
  const float* v = (const float*)d_in[2];
  const float* Wq = (const float*)d_in[3];
  const float* bq = (const float*)d_in[4];
  const float* Wk = (const float*)d_in[5];
  const float* bk = (const float*)d_in[6];
  const float* Wv = (const float*)d_in[7];
  const float* bv = (const float*)d_in[8];
  float* out = (float*)d_out;
  char* ws = (char*)d_ws;

  // Workspace layout (bytes). Total: 106,955,008 (unchanged, known ok).
  // scales @0 (256B); Wt @256 (6MB);
  // qb/kb/vb @6,291,712 (3x16MB, dead after proj; P overlays this region)
  // P @6,291,712 (64MB bf16 -> ends 73,400,576)
  // vpT @73,400,576 (16MB bf16)
  // qp8 @90,177,792 (8MB fp8); kp8 @98,566,400 (8MB fp8)
  unsigned* scales = (unsigned*)ws;
  ushort_t* Wt = (ushort_t*)(ws + 256);
  ushort_t* qb = (ushort_t*)(ws + 6291712);
  ushort_t* kb = qb + 8388608;
  ushort_t* vb = kb + 8388608;
  ushort_t* P = qb;
  ushort_t* vpT = (ushort_t*)(ws + 73400576);
  unsigned char* qp8 = (unsigned char*)(ws + 90177792);
  unsigned char* kp8 = (unsigned char*)(ws + 98566400);

  hipMemsetAsync(scales, 0, 64, stream);
  absmax_k<<<dim3(64, 1, 3), 256, 0, stream>>>(Wq, Wk, Wv, scales);
  quant_w_k<<<dim3(32, 32, 3), 256, 0, stream>>>(Wq, Wk, Wv, scales, Wt);
  cast3_k<<<dim3(512, 1, 3), 256, 0, stream>>>(q, k, v, qb, kb, vb);

  // Merged projections, 256^2 8-phase kernel (bm-fastest grid):
  // each z: M=8192, N=1024, K=1024. z<2 -> fp8 qp8/kp8; z==2 -> bf16 vpT.
  gemm256_proj<<<dim3(32, 4, 3), 512, 0, stream>>>(qb, Wt, vpT, qp8, bq, bk,
                                                   bv);

  // logits = qp x kp^T / 32 via MX-fp8: M=N=2048, K=1024, batched over 4
  qk_fp8<<<dim3(16, 16, 4), 256, 0, stream>>>(qp8, kp8, P);

  softmax_k<<<8192, 256, 0, stream>>>(P);

  // out = P x vpT^T (bm-fastest): M=2048, N=1024, K=2048, fp32 store
  gemm_bt<2, 1><<<dim3(16, 8, 4), 256, 0, stream>>>(
      P, vpT, out, nullptr, nullptr, nullptr, nullptr, 2048, 1024, 1.0f,
      4194304L, 2097152L, 2097152L);
}

// Round 3
// 316.978 us; speedup vs baseline: 1.0117x; 1.0117x over previous
//
#include <hip/hip_runtime.h>
#include <stdint.h>

// B=4, S=2048, D_IN=D_MODEL=1024.
// Pipeline: absmax(W) -> quantize W^T bf16 -> cast q,k,v bf16 ->
//   merged proj GEMM (256^2 single-barrier read-ahead schedule; z<2 emits
//   qp/kp fp8-e4m3, z==2 stores vp^T bf16)
//   -> QK^T via MX-scaled fp8 MFMA (K=128, scale=1) -> softmax(bf16) -> PV bf16.
// fp8 is used ONLY where softmax averaging attenuates the noise (qp/kp);
// vp and P stay bf16 (their error enters the output unattenuated).

typedef unsigned short ushort_t;
typedef __attribute__((ext_vector_type(8))) short short8;
typedef __bf16 bf16x8 __attribute__((ext_vector_type(8)));
typedef __attribute__((ext_vector_type(4))) float floatx4;
typedef __attribute__((ext_vector_type(8))) int int8v;

__device__ __forceinline__ ushort_t f2bf(float x) {
  unsigned u = __float_as_uint(x);
  unsigned r = (u + 0x7fffu + ((u >> 16) & 1u)) >> 16;  // RNE
  return (ushort_t)r;
}
__device__ __forceinline__ float bf2f(ushort_t u) {
  return __uint_as_float(((unsigned)u) << 16);
}
__device__ __forceinline__ unsigned char f2fp8(float x) {
  // v_cvt_pk_fp8_f32 (RNE, saturating), take low byte
  return (unsigned char)(__builtin_amdgcn_cvt_pk_fp8_f32(x, x, 0, false) & 0xff);
}

__device__ __forceinline__ void gl_lds16(const void* g, void* l) {
  __builtin_amdgcn_global_load_lds(
      (const __attribute__((address_space(1))) unsigned int*)g,
      (__attribute__((address_space(3))) unsigned int*)l, 16, 0, 0);
}

// ---------------------------------------------------------------------------
// Proj GEMM: 256x256 tile, BK=64, 8 waves (2M x 4N). Single barrier per slot
// + read-ahead: slot p issues ds_reads for slot p+1's MFMA, then runs the
// current MFMA cluster (whose operands were loaded last slot -> compiler
// emits exact counted lgkmcnt, no hand lgkmcnt(0)). 8 slots per 2 K-tiles.
// STAGE positions and vmcnt(6)@slot4/8 are IDENTICAL to the round-2-verified
// schedule (same retire geometry). WAR margins proven per-slot: every LDS
// slot's reads are register-waited by an MM before the barrier preceding its
// restage. K-accumulation order unchanged -> bit-identical output.
// LDS: 2 dbuf x 256x64 bf16 x2 = 128 KiB -> 1 block/CU.
// ---------------------------------------------------------------------------

#define BARRIER()                        \
  {                                      \
    __builtin_amdgcn_sched_barrier(0);   \
    __builtin_amdgcn_s_barrier();        \
    __builtin_amdgcn_sched_barrier(0);   \
  }
#define WAIT_VM(n)                                         \
  {                                                        \
    asm volatile("s_waitcnt vmcnt(" #n ")" ::: "memory");  \
    __builtin_amdgcn_sched_barrier(0);                     \
  }

// Stage half h (128 rows) of K-tile (iter-base + c) into buf. c compile-const;
// gA/gB advance 128 elems (2 tiles) per iteration.
#define STAGE_A(c, h, buf)                                           \
  {                                                                  \
    gl_lds16(gA + (h)*131072 + (c)*64,                               \
             sA + (buf)*16384 + ((h)*128 + wave * 8) * 64);          \
    gl_lds16(gA + (h)*131072 + 65536 + (c)*64,                       \
             sA + (buf)*16384 + ((h)*128 + 64 + wave * 8) * 64);     \
  }
#define STAGE_B(c, h, buf)                                           \
  {                                                                  \
    gl_lds16(gB + (h)*131072 + (c)*64,                               \
             sB + (buf)*16384 + ((h)*128 + wave * 8) * 64);          \
    gl_lds16(gB + (h)*131072 + 65536 + (c)*64,                       \
             sB + (buf)*16384 + ((h)*128 + 64 + wave * 8) * 64);     \
  }

// A fragment rows: qm*128 + wm*64 + mi*16 + fr; all terms but fr are 0 mod 8,
// so the XOR chunk term depends only on fr&7 -> addresses are separable into
// (aBase + xs_s) + compile-time immediates.
#define RD_A(dst, buf, qm)                                                   \
  {                                                                          \
    _Pragma("unroll") for (int mi = 0; mi < 4; ++mi) {                       \
      dst[mi][0] =                                                           \
          *(const bf16x8*)&sA[(buf)*16384 + (qm)*8192 + mi * 1024 + aB0];    \
      dst[mi][1] =                                                           \
          *(const bf16x8*)&sA[(buf)*16384 + (qm)*8192 + mi * 1024 + aB1];    \
    }                                                                        \
  }
#define RD_B(dst, buf, qn)                                                   \
  {                                                                          \
    _Pragma("unroll") for (int ni = 0; ni < 2; ++ni) {                       \
      dst[ni][0] =                                                           \
          *(const bf16x8*)&sB[(buf)*16384 + (qn)*8192 + ni * 1024 + bB0];    \
      dst[ni][1] =                                                           \
          *(const bf16x8*)&sB[(buf)*16384 + (qn)*8192 + ni * 1024 + bB1];    \
    }                                                                        \
  }
#define MM(qm, qn, AR, BR)                                                   \
  {                                                                          \
    __builtin_amdgcn_s_setprio(1);                                           \
    _Pragma("unroll") for (int s = 0; s < 2; ++s)                            \
        _Pragma("unroll") for (int mi = 0; mi < 4; ++mi)                     \
            _Pragma("unroll") for (int ni = 0; ni < 2; ++ni) acc[qm][qn][mi] \
                [ni] = __builtin_amdgcn_mfma_f32_16x16x32_bf16(              \
                    AR[mi][s], BR[ni][s], acc[qm][qn][mi][ni], 0, 0, 0);     \
    __builtin_amdgcn_s_setprio(0);                                           \
  }

__global__ __launch_bounds__(512, 2) void gemm256_proj(
    const ushort_t* __restrict__ A, const ushort_t* __restrict__ Bt,
    void* __restrict__ Cv, void* __restrict__ Cv8,
    const float* __restrict__ bias0, const float* __restrict__ bias1,
    const float* __restrict__ bias2) {
  __shared__ __attribute__((aligned(16))) ushort_t sA[2 * 256 * 64];
  __shared__ __attribute__((aligned(16))) ushort_t sB[2 * 256 * 64];

  const int t = threadIdx.x;
  const int lane = t & 63;
  const int wave = t >> 6;   // 0..7
  const int wm = wave >> 2;  // 0..1
  const int wn = wave & 3;   // 0..3
  const int bm = blockIdx.x; // 0..31 (bm-fastest: bn-sharers land on same XCD)
  const int bn = blockIdx.y; // 0..3
  const int bz = blockIdx.z; // 0..2

  const ushort_t* Ab = A + (long)bz * 8388608L;   // 8192*1024
  const ushort_t* Bb = Bt + (long)bz * 1048576L;  // 1024*1024

  const long a_row0 = (long)bm * 256;
  const long b_row0 = (long)bn * 256;

  // Staging geometry: 64 rows x 8 chunks(16B) per issue (512 thr x 16B).
  // XOR swizzle: LDS[row][chunk] holds global[row][chunk ^ (row&7)].
  const int crow = t >> 3;                  // 0..63
  const int schunk = (t & 7) ^ (crow & 7);  // swizzled global chunk
  const ushort_t* gA = Ab + (a_row0 + crow) * 1024 + schunk * 8;
  const ushort_t* gB = Bb + (b_row0 + crow) * 1024 + schunk * 8;

  floatx4 acc[2][2][4][2];
#pragma unroll
  for (int a = 0; a < 2; ++a)
#pragma unroll
    for (int b = 0; b < 2; ++b)
#pragma unroll
      for (int c = 0; c < 4; ++c)
#pragma unroll
        for (int d = 0; d < 2; ++d) acc[a][b][c][d] = {0.f, 0.f, 0.f, 0.f};

  const int fr = lane & 15;
  const int fg = lane >> 4;  // 0..3: which 16B chunk within a 32-k step

  // Separable LDS read addresses (see note at RD_A).
  const int xs0 = (fg ^ (fr & 7)) * 8;
  const int xs1 = ((4 + fg) ^ (fr & 7)) * 8;
  const int aB0 = (wm * 64 + fr) * 64 + xs0;
  const int aB1 = (wm * 64 + fr) * 64 + xs1;
  const int bB0 = (wn * 32 + fr) * 64 + xs0;
  const int bB1 = (wn * 32 + fr) * 64 + xs1;

  bf16x8 aX[4][2], aY[4][2], b0[2][2], b1[2][2];

  // Prologue: tile0 full + {A0,B0,B1} of tile1; A1(1) staged in slot1.
  STAGE_A(0, 0, 0);
  STAGE_A(0, 1, 0);
  STAGE_B(0, 0, 0);
  STAGE_B(0, 1, 0);
  STAGE_A(1, 0, 1);
  STAGE_B(1, 0, 1);
  STAGE_B(1, 1, 1);
  WAIT_VM(6);  // 14 loads issued; tile0 (oldest 8) complete
  BARRIER();

#pragma unroll 1
  for (int i = 0; i < 7; ++i) {
    // slot1: MM q00(t0); prefetch B1(buf0) for slot2
    STAGE_A(1, 1, 1);  // A1 of tile t0+1
    RD_A(aX, 0, 0);
    RD_B(b0, 0, 0);
    RD_B(b1, 0, 1);
    MM(0, 0, aX, b0);
    BARRIER();
    // slot2: MM q01; prefetch A1(buf0) for slot3
    STAGE_A(2, 0, 0);  // A0 of t0+2
    RD_A(aY, 0, 1);
    MM(0, 1, aX, b1);
    BARRIER();
    // slot3: MM q10 (operands all resident)
    STAGE_B(2, 0, 0);  // B0 of t0+2
    MM(1, 0, aY, b0);
    BARRIER();
    // slot4: MM q11; retire tile t0+1
    STAGE_B(2, 1, 0);  // B1 of t0+2
    MM(1, 1, aY, b1);
    WAIT_VM(6);  // tile t0+1 complete; 3 halves of t0+2 in flight
    BARRIER();
    // slot5: MM q00(t0+1) (serial read: buf1 just became readable)
    STAGE_A(2, 1, 0);  // A1 of t0+2
    RD_A(aX, 1, 0);
    RD_B(b0, 1, 0);
    RD_B(b1, 1, 1);
    MM(0, 0, aX, b0);
    BARRIER();
    // slot6
    STAGE_A(3, 0, 1);  // A0 of t0+3
    RD_A(aY, 1, 1);
    MM(0, 1, aX, b1);
    BARRIER();
    // slot7
    STAGE_B(3, 0, 1);  // B0 of t0+3
    MM(1, 0, aY, b0);
    BARRIER();
    // slot8
    STAGE_B(3, 1, 1);  // B1 of t0+3
    MM(1, 1, aY, b1);
    WAIT_VM(6);  // tile t0+2 complete; 3 halves of t0+3 in flight
    BARRIER();
    gA += 128;
    gB += 128;
  }

  // Epilogue: tiles 14 (buf0), 15 (buf1); gA/gB at k=896.
  STAGE_A(1, 1, 1);  // A1 of tile15 (last half)
  RD_A(aX, 0, 0);
  RD_B(b0, 0, 0);
  RD_B(b1, 0, 1);
  MM(0, 0, aX, b0);
  BARRIER();
  RD_A(aY, 0, 1);
  MM(0, 1, aX, b1);
  BARRIER();
  MM(1, 0, aY, b0);
  BARRIER();
  MM(1, 1, aY, b1);
  WAIT_VM(0);  // drain: tile 15 fully staged
  BARRIER();
  // tile15: no further LDS writes -> no barriers needed
  RD_A(aX, 1, 0);
  RD_B(b0, 1, 0);
  RD_B(b1, 1, 1);
  MM(0, 0, aX, b0);
  RD_A(aY, 1, 1);
  MM(0, 1, aX, b1);
  MM(1, 0, aY, b0);
  MM(1, 1, aY, b1);

  // C/D layout: row=(lane>>4)*4+reg, col=lane&15  [m89/m91]
  const int r0v = fg * 4;
  const float* bias = (bz == 0) ? bias0 : (bz == 1 ? bias1 : bias2);
  unsigned char* C8 = (unsigned char*)Cv8 + (long)bz * 8388608L;
  ushort_t* CvpT = (ushort_t*)Cv;

#pragma unroll
  for (int qm = 0; qm < 2; ++qm)
#pragma unroll
    for (int qn = 0; qn < 2; ++qn)
#pragma unroll
      for (int mi = 0; mi < 4; ++mi)
#pragma unroll
        for (int ni = 0; ni < 2; ++ni) {
          long gm0 = a_row0 + qm * 128 + wm * 64 + mi * 16 + r0v;
          long gn = b_row0 + qn * 128 + wn * 32 + ni * 16 + fr;
          float vv[4];
#pragma unroll
          for (int r = 0; r < 4; ++r)
            vv[r] = acc[qm][qn][mi][ni][r] + bias[gn];
          if (bz == 2) {
            // vp^T[b][gn][s]: r=0..3 contiguous in s; 8B packed store
            long b = gm0 >> 11, s = gm0 & 2047;
            ushort4 u4;
            u4.x = f2bf(vv[0]);
            u4.y = f2bf(vv[1]);
            u4.z = f2bf(vv[2]);
            u4.w = f2bf(vv[3]);
            *(ushort4*)&CvpT[b * (2048L * 1024L) + gn * 2048L + s] = u4;
          } else {
            // fp8 e4m3 store: qp8/kp8 [8192][1024] row-major
#pragma unroll
            for (int r = 0; r < 4; ++r) C8[(gm0 + r) * 1024 + gn] = f2fp8(vv[r]);
          }
        }
}

#define BM 128
#define BN 128
#define BK 64

// CMODE: 2 = fp32 store Cz[gm*ldc+gn]  (PV GEMM)
// SWAP:  1 = bm from blockIdx.x (bm-fastest for XCD A-stripe sharing)
template <int CMODE, int SWAP>
__global__ __launch_bounds__(256, 2) void gemm_bt(
    const ushort_t* __restrict__ A, const ushort_t* __restrict__ Bt,
    void* __restrict__ Cv, void* __restrict__ Cv8,
    const float* __restrict__ bias0, const float* __restrict__ bias1,
    const float* __restrict__ bias2, int K, int ldc, float alpha, long strideA,
    long strideB, long strideC) {
  __shared__ __attribute__((aligned(16))) ushort_t sA[BM * BK];
  __shared__ __attribute__((aligned(16))) ushort_t sB[BN * BK];

  const int t = threadIdx.x;
  const int lane = t & 63;
  const int wave = t >> 6;
  const int bm = SWAP ? blockIdx.x : blockIdx.y;
  const int bn = SWAP ? blockIdx.y : blockIdx.x;
  const int bz = blockIdx.z;

  const ushort_t* Ab = A + (long)bz * strideA;
  const ushort_t* Bb = Bt + (long)bz * strideB;

  const long a_row0 = (long)bm * BM;
  const long b_row0 = (long)bn * BN;

  // Staging: 32 rows x 8 chunks(16B) per issue; 4 issues per matrix.
  // XOR swizzle: LDS[row][chunk] holds global[row][chunk ^ (row&7)].
  const int crow = t >> 3;                  // 0..31
  const int schunk = (t & 7) ^ (crow & 7);  // swizzled global chunk

  const ushort_t* gA = Ab + (a_row0 + crow) * (long)K + schunk * 8;
  const ushort_t* gB = Bb + (b_row0 + crow) * (long)K + schunk * 8;

  ushort_t* lA = sA + wave * 512;  // + issue*2048; HW adds lane*16B
  ushort_t* lB = sB + wave * 512;

  floatx4 acc[4][4];
#pragma unroll
  for (int i = 0; i < 4; ++i)
#pragma unroll
    for (int j = 0; j < 4; ++j) acc[i][j] = {0.f, 0.f, 0.f, 0.f};

  const int wm = (wave & 1) * 64;
  const int wn = (wave >> 1) * 64;
  const int fr = lane & 15;
  const int fg = lane >> 4;  // 0..3: which 16B chunk within a 32-k step

  int offA[2][4], offB[2][4];
#pragma unroll
  for (int s = 0; s < 2; ++s)
#pragma unroll
    for (int i = 0; i < 4; ++i) {
      int rowA = wm + i * 16 + fr;
      int rowB = wn + i * 16 + fr;
      int cg = s * 4 + fg;
      offA[s][i] = rowA * BK + ((cg ^ (rowA & 7)) * 8);
      offB[s][i] = rowB * BK + ((cg ^ (rowB & 7)) * 8);
    }

  for (int k0 = 0; k0 < K; k0 += BK) {
#pragma unroll
    for (int i = 0; i < 4; ++i) {
      gl_lds16(gA + (long)i * 32 * K, lA + i * 2048);
      gl_lds16(gB + (long)i * 32 * K, lB + i * 2048);
    }
    gA += BK;
    gB += BK;
    __syncthreads();  // staging complete

#pragma unroll
    for (int s = 0; s < 2; ++s) {
      bf16x8 af[4], bfr[4];
#pragma unroll
      for (int i = 0; i < 4; ++i) {
        af[i] = *(const bf16x8*)&sA[offA[s][i]];
        bfr[i] = *(const bf16x8*)&sB[offB[s][i]];
      }
#pragma unroll
      for (int mi = 0; mi < 4; ++mi)
#pragma unroll
        for (int ni = 0; ni < 4; ++ni)
          acc[mi][ni] = __builtin_amdgcn_mfma_f32_16x16x32_bf16(
              af[mi], bfr[ni], acc[mi][ni], 0, 0, 0);
    }
    __syncthreads();  // reads done before next stage overwrites
  }

  // C/D layout: row=(lane>>4)*4+reg, col=lane&15  [m89/m91]
  const int r0 = fg * 4;
  const int cc = fr;
  float* Cz32 = (float*)Cv + (long)bz * strideC;

#pragma unroll
  for (int mi = 0; mi < 4; ++mi) {
#pragma unroll
    for (int ni = 0; ni < 4; ++ni) {
      long gm0 = a_row0 + wm + mi * 16 + r0;
      long gn = b_row0 + wn + ni * 16 + cc;
      float vv[4];
#pragma unroll
      for (int r = 0; r < 4; ++r) vv[r] = acc[mi][ni][r] * alpha;
      if (CMODE == 2) {
#pragma unroll
        for (int r = 0; r < 4; ++r) Cz32[(gm0 + r) * ldc + gn] = vv[r];
      }
    }
  }
}

// QK^T with MX-scaled fp8 MFMA: K=128/instr, scale=2^0 (E8M0 127).
// A=qp8, B=kp8, both [4][2048][1024] fp8 e4m3; P bf16 [4][2048][2048], /32.
__global__ __launch_bounds__(256, 2) void qk_fp8(
    const unsigned char* __restrict__ Q8, const unsigned char* __restrict__ K8,
    ushort_t* __restrict__ P) {
  __shared__ __attribute__((aligned(16))) unsigned char sA[128 * 128];
  __shared__ __attribute__((aligned(16))) unsigned char sB[128 * 128];
  const int t = threadIdx.x;
  const int lane = t & 63, wave = t >> 6;
  const int bm = blockIdx.x, bn = blockIdx.y, bz = blockIdx.z;

  const unsigned char* Ab = Q8 + (long)bz * 2097152L + (long)bm * 128 * 1024;
  const unsigned char* Bb = K8 + (long)bz * 2097152L + (long)bn * 128 * 1024;

  // Staging: row = 128 B (BK=128 fp8). 256 thr x 16B = 32 rows/issue, 4 issues.
  const int crow = t >> 3;
  const int schunk = (t & 7) ^ (crow & 7);
  const unsigned char* gA = Ab + crow * 1024 + schunk * 16;
  const unsigned char* gB = Bb + crow * 1024 + schunk * 16;
  unsigned char* lA = sA + wave * 1024;  // + issue*4096; HW adds lane*16B
  unsigned char* lB = sB + wave * 1024;

  floatx4 acc[4][4];
#pragma unroll
  for (int i = 0; i < 4; ++i)
#pragma unroll
    for (int j = 0; j < 4; ++j) acc[i][j] = {0.f, 0.f, 0.f, 0.f};

  const int wm = (wave & 1) * 64;
  const int wn = (wave >> 1) * 64;
  const int fr = lane & 15;
  const int fg = lane >> 4;  // quad: k-bytes [fg*32, fg*32+32)

  int offA[4][2], offB[4][2];
#pragma unroll
  for (int i = 0; i < 4; ++i) {
    int rA = wm + i * 16 + fr;
    int rB = wn + i * 16 + fr;
    offA[i][0] = rA * 128 + (((2 * fg) ^ (rA & 7)) * 16);
    offA[i][1] = rA * 128 + (((2 * fg + 1) ^ (rA & 7)) * 16);
    offB[i][0] = rB * 128 + (((2 * fg) ^ (rB & 7)) * 16);
    offB[i][1] = rB * 128 + (((2 * fg + 1) ^ (rB & 7)) * 16);
  }

  for (int k0 = 0; k0 < 1024; k0 += 128) {
#pragma unroll
    for (int i = 0; i < 4; ++i) {
      gl_lds16(gA + (long)i * 32 * 1024, lA + i * 4096);
      gl_lds16(gB + (long)i * 32 * 1024, lB + i * 4096);
    }
    gA += 128;
    gB += 128;
    __syncthreads();

    int8v af[4], bfr[4];
#pragma unroll
    for (int i = 0; i < 4; ++i) {
      int4 lo = *(const int4*)&sA[offA[i][0]];
      int4 hi = *(const int4*)&sA[offA[i][1]];
      af[i][0] = lo.x; af[i][1] = lo.y; af[i][2] = lo.z; af[i][3] = lo.w;
      af[i][4] = hi.x; af[i][5] = hi.y; af[i][6] = hi.z; af[i][7] = hi.w;
      int4 lo2 = *(const int4*)&sB[offB[i][0]];
      int4 hi2 = *(const int4*)&sB[offB[i][1]];
      bfr[i][0] = lo2.x; bfr[i][1] = lo2.y; bfr[i][2] = lo2.z; bfr[i][3] = lo2.w;
      bfr[i][4] = hi2.x; bfr[i][5] = hi2.y; bfr[i][6] = hi2.z; bfr[i][7] = hi2.w;
    }
#pragma unroll
    for (int mi = 0; mi < 4; ++mi)
#pragma unroll
      for (int ni = 0; ni < 4; ++ni)
        acc[mi][ni] = __builtin_amdgcn_mfma_scale_f32_16x16x128_f8f6f4(
            af[mi], bfr[ni], acc[mi][ni], 0, 0, 0, 127, 0, 127);
    __syncthreads();
  }

  const int r0 = fg * 4;
  const int cc = fr;
#pragma unroll
  for (int mi = 0; mi < 4; ++mi)
#pragma unroll
    for (int ni = 0; ni < 4; ++ni)
#pragma unroll
      for (int r = 0; r < 4; ++r) {
        long gm = (long)bm * 128 + wm + mi * 16 + r0 + r;
        long gn = (long)bn * 128 + wn + ni * 16 + cc;
        P[(long)bz * 4194304L + gm * 2048 + gn] =
            f2bf(acc[mi][ni][r] * 0.03125f);
      }
}

__global__ __launch_bounds__(256) void absmax_k(
    const float* __restrict__ W0, const float* __restrict__ W1,
    const float* __restrict__ W2, unsigned* __restrict__ outv) {
  const float* W = blockIdx.z == 0 ? W0 : (blockIdx.z == 1 ? W1 : W2);
  float m = 0.f;
  const long n = 1024L * 1024L;
  for (long i = (long)blockIdx.x * blockDim.x + threadIdx.x; i < n;
       i += (long)gridDim.x * blockDim.x)
    m = fmaxf(m, fabsf(W[i]));
  for (int off = 32; off; off >>= 1) m = fmaxf(m, __shfl_xor(m, off));
  __shared__ float red[4];
  int lane = threadIdx.x & 63, wave = threadIdx.x >> 6;
  if (lane == 0) red[wave] = m;
  __syncthreads();
  if (threadIdx.x == 0) {
    m = fmaxf(fmaxf(red[0], red[1]), fmaxf(red[2], red[3]));
    atomicMax(&outv[blockIdx.z], __float_as_uint(m));  // positive: uint order
  }
}

__global__ __launch_bounds__(256) void quant_w_k(
    const float* __restrict__ W0, const float* __restrict__ W1,
    const float* __restrict__ W2, const unsigned* __restrict__ scales,
    ushort_t* __restrict__ Wt) {
  const int z = blockIdx.z;
  const float* W = z == 0 ? W0 : (z == 1 ? W1 : W2);
  const float s = __uint_as_float(scales[z]) * (1.0f / 128.0f);
  __shared__ float tile[32][33];
  const int tx = threadIdx.x & 31, ty = threadIdx.x >> 5;
  const int k0 = blockIdx.y * 32, n0 = blockIdx.x * 32;
#pragma unroll
  for (int i = 0; i < 4; ++i)
    tile[ty + i * 8][tx] = W[(long)(k0 + ty + i * 8) * 1024 + n0 + tx];
  __syncthreads();
  ushort_t* wt = Wt + (long)z * 1024 * 1024;
#pragma unroll
  for (int i = 0; i < 4; ++i) {
    float w = tile[tx][ty + i * 8];
    float qv = rintf(w / s) * s;  // rintf = RNE = jnp.round
    wt[(long)(n0 + ty + i * 8) * 1024 + k0 + tx] = f2bf(qv);
  }
}

__global__ __launch_bounds__(256) void cast3_k(
    const float* __restrict__ q, const float* __restrict__ k,
    const float* __restrict__ v, ushort_t* __restrict__ qb,
    ushort_t* __restrict__ kb, ushort_t* __restrict__ vb) {
  const int z = blockIdx.z;
  const float4* src = (const float4*)(z == 0 ? q : (z == 1 ? k : v));
  ushort_t* dst = z == 0 ? qb : (z == 1 ? kb : vb);
  const long nv = (4L * 2048 * 1024) / 4;
  for (long i = (long)blockIdx.x * blockDim.x + threadIdx.x; i < nv;
       i += (long)gridDim.x * blockDim.x) {
    float4 f = src[i];
    ushort4 u4;
    u4.x = f2bf(f.x); u4.y = f2bf(f.y); u4.z = f2bf(f.z); u4.w = f2bf(f.w);
    *(ushort4*)(dst + i * 4) = u4;
  }
}

__global__ __launch_bounds__(256) void softmax_k(ushort_t* __restrict__ P) {
  const long row = blockIdx.x;
  ushort_t* p = P + row * 2048;
  const int t = threadIdx.x;
  const int lane = t & 63, wave = t >> 6;
  short8 v8 = *(const short8*)&p[t * 8];
  float x[8];
#pragma unroll
  for (int j = 0; j < 8; ++j) x[j] = bf2f((ushort_t)v8[j]);
  float m = x[0];
#pragma unroll
  for (int j = 1; j < 8; ++j) m = fmaxf(m, x[j]);
  for (int off = 32; off; off >>= 1) m = fmaxf(m, __shfl_xor(m, off));
  __shared__ float rmax[4], rsum[4];
  if (lane == 0) rmax[wave] = m;
  __syncthreads();
  m = fmaxf(fmaxf(rmax[0], rmax[1]), fmaxf(rmax[2], rmax[3]));
  float s = 0.f;
#pragma unroll
  for (int j = 0; j < 8; ++j) {
    x[j] = __expf(x[j] - m);
    s += x[j];
  }
  for (int off = 32; off; off >>= 1) s += __shfl_xor(s, off);
  if (lane == 0) rsum[wave] = s;
  __syncthreads();
  s = rsum[0] + rsum[1] + rsum[2] + rsum[3];
  float inv = 1.0f / s;
  short8 o8;
#pragma unroll
  for (int j = 0; j < 8; ++j) o8[j] = (short)f2bf(x[j] * inv);
  *(short8*)&p[t * 8] = o8;
}

extern "C" void kernel_launch(void* const* d_in, const int* in_sizes, int n_in,
                              void* d_out, int out_size, void* d_ws,
                              size_t ws_size, hipStream_t stream) {
  const float* q = (const float*)d_in[0];
  const float* k = (const float*)d_in[1];
  const float* v = (const float*)d_in[2];
  const float* Wq = (const float*)d_in[3];
  const float* bq = (const float*)d_in[4];
  const float* Wk = (const float*)d_in[5];
  const float* bk = (const float*)d_in[6];
  const float* Wv = (const float*)d_in[7];
  const float* bv = (const float*)d_in[8];
  float* out = (float*)d_out;
  char* ws = (char*)d_ws;

  // Workspace layout (bytes). Total: 106,955,008 (unchanged, known ok).
  // scales @0 (256B); Wt @256 (6MB);
  // qb/kb/vb @6,291,712 (3x16MB, dead after proj; P overlays this region)
  // P @6,291,712 (64MB bf16 -> ends 73,400,576)
  // vpT @73,400,576 (16MB bf16)
  // qp8 @90,177,792 (8MB fp8); kp8 @98,566,400 (8MB fp8)
  unsigned* scales = (unsigned*)ws;
  ushort_t* Wt = (ushort_t*)(ws + 256);
  ushort_t* qb = (ushort_t*)(ws + 6291712);
  ushort_t* kb = qb + 8388608;
  ushort_t* vb = kb + 8388608;
  ushort_t* P = qb;
  ushort_t* vpT = (ushort_t*)(ws + 73400576);
  unsigned char* qp8 = (unsigned char*)(ws + 90177792);
  unsigned char* kp8 = (unsigned char*)(ws + 98566400);

  hipMemsetAsync(scales, 0, 64, stream);
  absmax_k<<<dim3(64, 1, 3), 256, 0, stream>>>(Wq, Wk, Wv, scales);
  quant_w_k<<<dim3(32, 32, 3), 256, 0, stream>>>(Wq, Wk, Wv, scales, Wt);
  cast3_k<<<dim3(512, 1, 3), 256, 0, stream>>>(q, k, v, qb, kb, vb);

  // Merged projections, 256^2 read-ahead kernel (bm-fastest grid):
  // each z: M=8192, N=1024, K=1024. z<2 -> fp8 qp8/kp8; z==2 -> bf16 vpT.
  gemm256_proj<<<dim3(32, 4, 3), 512, 0, stream>>>(qb, Wt, vpT, qp8, bq, bk,
                                                   bv);

  // logits = qp x kp^T / 32 via MX-fp8: M=N=2048, K=1024, batched over 4
  qk_fp8<<<dim3(16, 16, 4), 256, 0, stream>>>(qp8, kp8, P);

  softmax_k<<<8192, 256, 0, stream>>>(P);

  // out = P x vpT^T (bm-fastest): M=2048, N=1024, K=2048, fp32 store
  gemm_bt<2, 1><<<dim3(16, 8, 4), 256, 0, stream>>>(
      P, vpT, out, nullptr, nullptr, nullptr, nullptr, 2048, 1024, 1.0f,
      4194304L, 2097152L, 2097152L);
}

// Round 4
// 310.759 us; speedup vs baseline: 1.0320x; 1.0200x over previous
//
#include <hip/hip_runtime.h>
#include <stdint.h>

// B=4, S=2048, D_IN=D_MODEL=1024.
// Pipeline: absmax(W) -> quantize W^T bf16 ->
//   merged proj GEMM reads q/k/v f32 DIRECTLY (reg-staged A with in-register
//   f32->bf16 cvt, T14 split + counted vmcnt; B via global_load_lds;
//   z<2 emits qp/kp fp8-e4m3, z==2 stores vp^T bf16)
//   -> QK^T via MX-scaled fp8 MFMA (K=128, scale=1) -> softmax(bf16) -> PV bf16.
// cast3_k eliminated: qb/kb/vb were consumed only by the proj GEMM, which has
// 85% HBM headroom -- the f32 fetch is free, the 144MB cast round-trip wasn't.

typedef unsigned short ushort_t;
typedef __attribute__((ext_vector_type(8))) short short8;
typedef __bf16 bf16x8 __attribute__((ext_vector_type(8)));
typedef __attribute__((ext_vector_type(4))) float floatx4;
typedef __attribute__((ext_vector_type(8))) int int8v;

__device__ __forceinline__ ushort_t f2bf(float x) {
  unsigned u = __float_as_uint(x);
  unsigned r = (u + 0x7fffu + ((u >> 16) & 1u)) >> 16;  // RNE
  return (ushort_t)r;
}
__device__ __forceinline__ float bf2f(ushort_t u) {
  return __uint_as_float(((unsigned)u) << 16);
}
__device__ __forceinline__ unsigned char f2fp8(float x) {
  // v_cvt_pk_fp8_f32 (RNE, saturating), take low byte
  return (unsigned char)(__builtin_amdgcn_cvt_pk_fp8_f32(x, x, 0, false) & 0xff);
}
__device__ __forceinline__ int cvtpk_bf16(float a, float b) {
  // packed RNE f32->bf16: lo16 = cvt(a), hi16 = cvt(b)
  unsigned r;
  asm("v_cvt_pk_bf16_f32 %0, %1, %2" : "=v"(r) : "v"(a), "v"(b));
  return (int)r;
}

__device__ __forceinline__ void gl_lds16(const void* g, void* l) {
  __builtin_amdgcn_global_load_lds(
      (const __attribute__((address_space(1))) unsigned int*)g,
      (__attribute__((address_space(3))) unsigned int*)l, 16, 0, 0);
}

// ---------------------------------------------------------------------------
// Merged proj GEMM, 128x128 tile, BK=64, 4 waves (round-0-verified compute
// structure). A (q/k/v) is f32 in HBM: reg-staged (8x dwordx4/thread issued
// one K-tile ahead), converted via v_cvt_pk_bf16_f32, ds_write'd into the
// EXACT bf16 LDS image the old kernel had (same XOR swizzle). B (Wt bf16)
// stays global_load_lds. Barrier 1 per K-tile waits lgkmcnt(0) (A ds_writes)
// + vmcnt(8) (retires B's 4 gl_lds; the 8 A-prefetch loads stay in flight
// across the barrier = T14/T4). A-prefetch wraps (k0+64)&1023 so the vmcnt
// count is uniform at the last iteration (wrap re-reads are L3-hot).
// ---------------------------------------------------------------------------
__global__ __launch_bounds__(256, 2) void proj_f32a(
    const float* __restrict__ Aq, const float* __restrict__ Ak,
    const float* __restrict__ Av, const ushort_t* __restrict__ Bt,
    void* __restrict__ Cv, void* __restrict__ Cv8,
    const float* __restrict__ bias0, const float* __restrict__ bias1,
    const float* __restrict__ bias2) {
  __shared__ __attribute__((aligned(16))) ushort_t sA[128 * 64];
  __shared__ __attribute__((aligned(16))) ushort_t sB[128 * 64];

  const int t = threadIdx.x;
  const int lane = t & 63;
  const int wave = t >> 6;
  const int bm = blockIdx.x;  // bm-fastest: bn-sharers of A land on same XCD
  const int bn = blockIdx.y;
  const int bz = blockIdx.z;

  const float* Ab = bz == 0 ? Aq : (bz == 1 ? Ak : Av);
  const ushort_t* Bb = Bt + (long)bz * 1048576L;

  const long a_row0 = (long)bm * 128;
  const long b_row0 = (long)bn * 128;

  // --- B staging via gl_lds (unchanged from round-0): 32 rows x 8 chunks ---
  const int crow = t >> 3;                  // 0..31
  const int schunk = (t & 7) ^ (crow & 7);  // pre-swizzled global chunk
  const ushort_t* gB = Bb + (b_row0 + crow) * 1024 + schunk * 8;
  ushort_t* lB = sB + wave * 512;  // + issue*2048; HW adds lane*16B

  // --- A reg-staging: thread owns 8 f32 (one bf16 chunk) of 4 rows ---
  // row(k) = k*32 + (t>>3), chunk = t&7. ds_write target reproduces the
  // old LDS image: sA[row*64 + ((chunk ^ (row&7))*8)]; row&7 == arow&7.
  const int arow = t >> 3;  // 0..31
  const int achk = t & 7;
  const float* gA = Ab + (a_row0 + arow) * 1024 + achk * 8;
  int awr[4];
#pragma unroll
  for (int k = 0; k < 4; ++k)
    awr[k] = (k * 32 + arow) * 64 + ((achk ^ (arow & 7)) * 8);

  floatx4 acc[4][4];
#pragma unroll
  for (int i = 0; i < 4; ++i)
#pragma unroll
    for (int j = 0; j < 4; ++j) acc[i][j] = {0.f, 0.f, 0.f, 0.f};

  const int wm = (wave & 1) * 64;
  const int wn = (wave >> 1) * 64;
  const int fr = lane & 15;
  const int fg = lane >> 4;

  int offA[2][4], offB[2][4];
#pragma unroll
  for (int s = 0; s < 2; ++s)
#pragma unroll
    for (int i = 0; i < 4; ++i) {
      int rowA = wm + i * 16 + fr;
      int rowB = wn + i * 16 + fr;
      int cg = s * 4 + fg;
      offA[s][i] = rowA * 64 + ((cg ^ (rowA & 7)) * 8);
      offB[s][i] = rowB * 64 + ((cg ^ (rowB & 7)) * 8);
    }

  float4 aL[8];
  // Prologue: issue A(k0=0) loads.
#pragma unroll
  for (int k = 0; k < 4; ++k) {
    aL[2 * k] = *(const float4*)(gA + (long)k * 32 * 1024);
    aL[2 * k + 1] = *(const float4*)(gA + (long)k * 32 * 1024 + 4);
  }

#pragma unroll 1
  for (int k0 = 0; k0 < 1024; k0 += 64) {
    // (1) convert + ds_write A(k0); reg deps on aL force the vmcnt wait.
#pragma unroll
    for (int k = 0; k < 4; ++k) {
      int4 w;
      w.x = cvtpk_bf16(aL[2 * k].x, aL[2 * k].y);
      w.y = cvtpk_bf16(aL[2 * k].z, aL[2 * k].w);
      w.z = cvtpk_bf16(aL[2 * k + 1].x, aL[2 * k + 1].y);
      w.w = cvtpk_bf16(aL[2 * k + 1].z, aL[2 * k + 1].w);
      *(int4*)&sA[awr[k]] = w;
    }
    // (2) B staging for this K-tile.
#pragma unroll
    for (int i = 0; i < 4; ++i)
      gl_lds16(gB + (long)i * 32 * 1024 + k0, lB + i * 2048);
    // Pin issue order: the 8 A-prefetch loads must be YOUNGER than B's gl_lds
    // so vmcnt(8) below provably retires the gl_lds.
    __builtin_amdgcn_sched_barrier(0);
    // (3) A prefetch for next K-tile (wrap keeps vmcnt uniform; L3-hot).
    {
      const long kn = (k0 + 64) & 1023;
#pragma unroll
      for (int k = 0; k < 4; ++k) {
        aL[2 * k] = *(const float4*)(gA + (long)k * 32 * 1024 + kn);
        aL[2 * k + 1] = *(const float4*)(gA + (long)k * 32 * 1024 + kn + 4);
      }
    }
    // (4) ds_writes visible + B landed; A-prefetch (8) stays in flight.
    asm volatile("s_waitcnt lgkmcnt(0) vmcnt(8)" ::: "memory");
    __builtin_amdgcn_sched_barrier(0);
    __builtin_amdgcn_s_barrier();
    __builtin_amdgcn_sched_barrier(0);

    // (5) compute: identical to round-0 structure.
#pragma unroll
    for (int s = 0; s < 2; ++s) {
      bf16x8 af[4], bfr[4];
#pragma unroll
      for (int i = 0; i < 4; ++i) {
        af[i] = *(const bf16x8*)&sA[offA[s][i]];
        bfr[i] = *(const bf16x8*)&sB[offB[s][i]];
      }
#pragma unroll
      for (int mi = 0; mi < 4; ++mi)
#pragma unroll
        for (int ni = 0; ni < 4; ++ni)
          acc[mi][ni] = __builtin_amdgcn_mfma_f32_16x16x32_bf16(
              af[mi], bfr[ni], acc[mi][ni], 0, 0, 0);
    }
    // (6) reads complete (register-resolved before MFMA issue) -> barrier,
    // then next iteration may overwrite sA/sB.
    __builtin_amdgcn_sched_barrier(0);
    __builtin_amdgcn_s_barrier();
    __builtin_amdgcn_sched_barrier(0);
  }

  // C/D layout: row=(lane>>4)*4+reg, col=lane&15  [m89/m91]
  const int r0 = fg * 4;
  const int cc = fr;
  const float* bias = bz == 0 ? bias0 : (bz == 1 ? bias1 : bias2);
  unsigned char* C8 = (unsigned char*)Cv8 + (long)bz * 8388608L;
  ushort_t* CvpT = (ushort_t*)Cv;

#pragma unroll
  for (int mi = 0; mi < 4; ++mi) {
#pragma unroll
    for (int ni = 0; ni < 4; ++ni) {
      long gm0 = a_row0 + wm + mi * 16 + r0;
      long gn = b_row0 + wn + ni * 16 + cc;
      float vv[4];
#pragma unroll
      for (int r = 0; r < 4; ++r) vv[r] = acc[mi][ni][r] + bias[gn];
      if (bz == 2) {
        // vp^T[b][gn][s]: r=0..3 contiguous in s; 8B packed store
        long b = gm0 >> 11, s = gm0 & 2047;
        ushort4 u4;
        u4.x = f2bf(vv[0]);
        u4.y = f2bf(vv[1]);
        u4.z = f2bf(vv[2]);
        u4.w = f2bf(vv[3]);
        *(ushort4*)&CvpT[b * (2048L * 1024L) + gn * 2048L + s] = u4;
      } else {
        // fp8 e4m3 store: qp8/kp8 [8192][1024] row-major
#pragma unroll
        for (int r = 0; r < 4; ++r) C8[(gm0 + r) * 1024 + gn] = f2fp8(vv[r]);
      }
    }
  }
}

#define BM 128
#define BN 128
#define BK 64

// CMODE: 2 = fp32 store Cz[gm*ldc+gn]  (PV GEMM)
// SWAP:  1 = bm from blockIdx.x (bm-fastest for XCD A-stripe sharing)
template <int CMODE, int SWAP>
__global__ __launch_bounds__(256, 2) void gemm_bt(
    const ushort_t* __restrict__ A, const ushort_t* __restrict__ Bt,
    void* __restrict__ Cv, void* __restrict__ Cv8,
    const float* __restrict__ bias0, const float* __restrict__ bias1,
    const float* __restrict__ bias2, int K, int ldc, float alpha, long strideA,
    long strideB, long strideC) {
  __shared__ __attribute__((aligned(16))) ushort_t sA[BM * BK];
  __shared__ __attribute__((aligned(16))) ushort_t sB[BN * BK];

  const int t = threadIdx.x;
  const int lane = t & 63;
  const int wave = t >> 6;
  const int bm = SWAP ? blockIdx.x : blockIdx.y;
  const int bn = SWAP ? blockIdx.y : blockIdx.x;
  const int bz = blockIdx.z;

  const ushort_t* Ab = A + (long)bz * strideA;
  const ushort_t* Bb = Bt + (long)bz * strideB;

  const long a_row0 = (long)bm * BM;
  const long b_row0 = (long)bn * BN;

  // Staging: 32 rows x 8 chunks(16B) per issue; 4 issues per matrix.
  // XOR swizzle: LDS[row][chunk] holds global[row][chunk ^ (row&7)].
  const int crow = t >> 3;                  // 0..31
  const int schunk = (t & 7) ^ (crow & 7);  // swizzled global chunk

  const ushort_t* gA = Ab + (a_row0 + crow) * (long)K + schunk * 8;
  const ushort_t* gB = Bb + (b_row0 + crow) * (long)K + schunk * 8;

  ushort_t* lA = sA + wave * 512;  // + issue*2048; HW adds lane*16B
  ushort_t* lB = sB + wave * 512;

  floatx4 acc[4][4];
#pragma unroll
  for (int i = 0; i < 4; ++i)
#pragma unroll
    for (int j = 0; j < 4; ++j) acc[i][j] = {0.f, 0.f, 0.f, 0.f};

  const int wm = (wave & 1) * 64;
  const int wn = (wave >> 1) * 64;
  const int fr = lane & 15;
  const int fg = lane >> 4;  // 0..3: which 16B chunk within a 32-k step

  int offA[2][4], offB[2][4];
#pragma unroll
  for (int s = 0; s < 2; ++s)
#pragma unroll
    for (int i = 0; i < 4; ++i) {
      int rowA = wm + i * 16 + fr;
      int rowB = wn + i * 16 + fr;
      int cg = s * 4 + fg;
      offA[s][i] = rowA * BK + ((cg ^ (rowA & 7)) * 8);
      offB[s][i] = rowB * BK + ((cg ^ (rowB & 7)) * 8);
    }

  for (int k0 = 0; k0 < K; k0 += BK) {
#pragma unroll
    for (int i = 0; i < 4; ++i) {
      gl_lds16(gA + (long)i * 32 * K, lA + i * 2048);
      gl_lds16(gB + (long)i * 32 * K, lB + i * 2048);
    }
    gA += BK;
    gB += BK;
    __syncthreads();  // staging complete

#pragma unroll
    for (int s = 0; s < 2; ++s) {
      bf16x8 af[4], bfr[4];
#pragma unroll
      for (int i = 0; i < 4; ++i) {
        af[i] = *(const bf16x8*)&sA[offA[s][i]];
        bfr[i] = *(const bf16x8*)&sB[offB[s][i]];
      }
#pragma unroll
      for (int mi = 0; mi < 4; ++mi)
#pragma unroll
        for (int ni = 0; ni < 4; ++ni)
          acc[mi][ni] = __builtin_amdgcn_mfma_f32_16x16x32_bf16(
              af[mi], bfr[ni], acc[mi][ni], 0, 0, 0);
    }
    __syncthreads();  // reads done before next stage overwrites
  }

  // C/D layout: row=(lane>>4)*4+reg, col=lane&15  [m89/m91]
  const int r0 = fg * 4;
  const int cc = fr;
  float* Cz32 = (float*)Cv + (long)bz * strideC;

#pragma unroll
  for (int mi = 0; mi < 4; ++mi) {
#pragma unroll
    for (int ni = 0; ni < 4; ++ni) {
      long gm0 = a_row0 + wm + mi * 16 + r0;
      long gn = b_row0 + wn + ni * 16 + cc;
      float vv[4];
#pragma unroll
      for (int r = 0; r < 4; ++r) vv[r] = acc[mi][ni][r] * alpha;
      if (CMODE == 2) {
#pragma unroll
        for (int r = 0; r < 4; ++r) Cz32[(gm0 + r) * ldc + gn] = vv[r];
      }
    }
  }
}

// QK^T with MX-scaled fp8 MFMA: K=128/instr, scale=2^0 (E8M0 127).
// A=qp8, B=kp8, both [4][2048][1024] fp8 e4m3; P bf16 [4][2048][2048], /32.
__global__ __launch_bounds__(256, 2) void qk_fp8(
    const unsigned char* __restrict__ Q8, const unsigned char* __restrict__ K8,
    ushort_t* __restrict__ P) {
  __shared__ __attribute__((aligned(16))) unsigned char sA[128 * 128];
  __shared__ __attribute__((aligned(16))) unsigned char sB[128 * 128];
  const int t = threadIdx.x;
  const int lane = t & 63, wave = t >> 6;
  const int bm = blockIdx.x, bn = blockIdx.y, bz = blockIdx.z;

  const unsigned char* Ab = Q8 + (long)bz * 2097152L + (long)bm * 128 * 1024;
  const unsigned char* Bb = K8 + (long)bz * 2097152L + (long)bn * 128 * 1024;

  // Staging: row = 128 B (BK=128 fp8). 256 thr x 16B = 32 rows/issue, 4 issues.
  const int crow = t >> 3;
  const int schunk = (t & 7) ^ (crow & 7);
  const unsigned char* gA = Ab + crow * 1024 + schunk * 16;
  const unsigned char* gB = Bb + crow * 1024 + schunk * 16;
  unsigned char* lA = sA + wave * 1024;  // + issue*4096; HW adds lane*16B
  unsigned char* lB = sB + wave * 1024;

  floatx4 acc[4][4];
#pragma unroll
  for (int i = 0; i < 4; ++i)
#pragma unroll
    for (int j = 0; j < 4; ++j) acc[i][j] = {0.f, 0.f, 0.f, 0.f};

  const int wm = (wave & 1) * 64;
  const int wn = (wave >> 1) * 64;
  const int fr = lane & 15;
  const int fg = lane >> 4;  // quad: k-bytes [fg*32, fg*32+32)

  int offA[4][2], offB[4][2];
#pragma unroll
  for (int i = 0; i < 4; ++i) {
    int rA = wm + i * 16 + fr;
    int rB = wn + i * 16 + fr;
    offA[i][0] = rA * 128 + (((2 * fg) ^ (rA & 7)) * 16);
    offA[i][1] = rA * 128 + (((2 * fg + 1) ^ (rA & 7)) * 16);
    offB[i][0] = rB * 128 + (((2 * fg) ^ (rB & 7)) * 16);
    offB[i][1] = rB * 128 + (((2 * fg + 1) ^ (rB & 7)) * 16);
  }

  for (int k0 = 0; k0 < 1024; k0 += 128) {
#pragma unroll
    for (int i = 0; i < 4; ++i) {
      gl_lds16(gA + (long)i * 32 * 1024, lA + i * 4096);
      gl_lds16(gB + (long)i * 32 * 1024, lB + i * 4096);
    }
    gA += 128;
    gB += 128;
    __syncthreads();

    int8v af[4], bfr[4];
#pragma unroll
    for (int i = 0; i < 4; ++i) {
      int4 lo = *(const int4*)&sA[offA[i][0]];
      int4 hi = *(const int4*)&sA[offA[i][1]];
      af[i][0] = lo.x; af[i][1] = lo.y; af[i][2] = lo.z; af[i][3] = lo.w;
      af[i][4] = hi.x; af[i][5] = hi.y; af[i][6] = hi.z; af[i][7] = hi.w;
      int4 lo2 = *(const int4*)&sB[offB[i][0]];
      int4 hi2 = *(const int4*)&sB[offB[i][1]];
      bfr[i][0] = lo2.x; bfr[i][1] = lo2.y; bfr[i][2] = lo2.z; bfr[i][3] = lo2.w;
      bfr[i][4] = hi2.x; bfr[i][5] = hi2.y; bfr[i][6] = hi2.z; bfr[i][7] = hi2.w;
    }
#pragma unroll
    for (int mi = 0; mi < 4; ++mi)
#pragma unroll
      for (int ni = 0; ni < 4; ++ni)
        acc[mi][ni] = __builtin_amdgcn_mfma_scale_f32_16x16x128_f8f6f4(
            af[mi], bfr[ni], acc[mi][ni], 0, 0, 0, 127, 0, 127);
    __syncthreads();
  }

  const int r0 = fg * 4;
  const int cc = fr;
#pragma unroll
  for (int mi = 0; mi < 4; ++mi)
#pragma unroll
    for (int ni = 0; ni < 4; ++ni)
#pragma unroll
      for (int r = 0; r < 4; ++r) {
        long gm = (long)bm * 128 + wm + mi * 16 + r0 + r;
        long gn = (long)bn * 128 + wn + ni * 16 + cc;
        P[(long)bz * 4194304L + gm * 2048 + gn] =
            f2bf(acc[mi][ni][r] * 0.03125f);
      }
}

__global__ __launch_bounds__(256) void absmax_k(
    const float* __restrict__ W0, const float* __restrict__ W1,
    const float* __restrict__ W2, unsigned* __restrict__ outv) {
  const float* W = blockIdx.z == 0 ? W0 : (blockIdx.z == 1 ? W1 : W2);
  float m = 0.f;
  const long n = 1024L * 1024L;
  for (long i = (long)blockIdx.x * blockDim.x + threadIdx.x; i < n;
       i += (long)gridDim.x * blockDim.x)
    m = fmaxf(m, fabsf(W[i]));
  for (int off = 32; off; off >>= 1) m = fmaxf(m, __shfl_xor(m, off));
  __shared__ float red[4];
  int lane = threadIdx.x & 63, wave = threadIdx.x >> 6;
  if (lane == 0) red[wave] = m;
  __syncthreads();
  if (threadIdx.x == 0) {
    m = fmaxf(fmaxf(red[0], red[1]), fmaxf(red[2], red[3]));
    atomicMax(&outv[blockIdx.z], __float_as_uint(m));  // positive: uint order
  }
}

__global__ __launch_bounds__(256) void quant_w_k(
    const float* __restrict__ W0, const float* __restrict__ W1,
    const float* __restrict__ W2, const unsigned* __restrict__ scales,
    ushort_t* __restrict__ Wt) {
  const int z = blockIdx.z;
  const float* W = z == 0 ? W0 : (z == 1 ? W1 : W2);
  const float s = __uint_as_float(scales[z]) * (1.0f / 128.0f);
  __shared__ float tile[32][33];
  const int tx = threadIdx.x & 31, ty = threadIdx.x >> 5;
  const int k0 = blockIdx.y * 32, n0 = blockIdx.x * 32;
#pragma unroll
  for (int i = 0; i < 4; ++i)
    tile[ty + i * 8][tx] = W[(long)(k0 + ty + i * 8) * 1024 + n0 + tx];
  __syncthreads();
  ushort_t* wt = Wt + (long)z * 1024 * 1024;
#pragma unroll
  for (int i = 0; i < 4; ++i) {
    float w = tile[tx][ty + i * 8];
    float qv = rintf(w / s) * s;  // rintf = RNE = jnp.round
    wt[(long)(n0 + ty + i * 8) * 1024 + k0 + tx] = f2bf(qv);
  }
}

__global__ __launch_bounds__(256) void softmax_k(ushort_t* __restrict__ P) {
  const long row = blockIdx.x;
  ushort_t* p = P + row * 2048;
  const int t = threadIdx.x;
  const int lane = t & 63, wave = t >> 6;
  short8 v8 = *(const short8*)&p[t * 8];
  float x[8];
#pragma unroll
  for (int j = 0; j < 8; ++j) x[j] = bf2f((ushort_t)v8[j]);
  float m = x[0];
#pragma unroll
  for (int j = 1; j < 8; ++j) m = fmaxf(m, x[j]);
  for (int off = 32; off; off >>= 1) m = fmaxf(m, __shfl_xor(m, off));
  __shared__ float rmax[4], rsum[4];
  if (lane == 0) rmax[wave] = m;
  __syncthreads();
  m = fmaxf(fmaxf(rmax[0], rmax[1]), fmaxf(rmax[2], rmax[3]));
  float s = 0.f;
#pragma unroll
  for (int j = 0; j < 8; ++j) {
    x[j] = __expf(x[j] - m);
    s += x[j];
  }
  for (int off = 32; off; off >>= 1) s += __shfl_xor(s, off);
  if (lane == 0) rsum[wave] = s;
  __syncthreads();
  s = rsum[0] + rsum[1] + rsum[2] + rsum[3];
  float inv = 1.0f / s;
  short8 o8;
#pragma unroll
  for (int j = 0; j < 8; ++j) o8[j] = (short)f2bf(x[j] * inv);
  *(short8*)&p[t * 8] = o8;
}

extern "C" void kernel_launch(void* const* d_in, const int* in_sizes, int n_in,
                              void* d_out, int out_size, void* d_ws,
                              size_t ws_size, hipStream_t stream) {
  const float* q = (const float*)d_in[0];
  const float* k = (const float*)d_in[1];
  const float* v = (const float*)d_in[2];
  const float* Wq = (const float*)d_in[3];
  const float* bq = (const float*)d_in[4];
  const float* Wk = (const float*)d_in[5];
  const float* bk = (const float*)d_in[6];
  const float* Wv = (const float*)d_in[7];
  const float* bv = (const float*)d_in[8];
  float* out = (float*)d_out;
  char* ws = (char*)d_ws;

  // Workspace layout (bytes). Total: 106,955,008 (unchanged, known ok).
  // scales @0 (256B); Wt @256 (6MB);
  // P @6,291,712 (64MB bf16 -> ends 73,400,576)  [qb/kb/vb eliminated]
  // vpT @73,400,576 (16MB bf16)
  // qp8 @90,177,792 (8MB fp8); kp8 @98,566,400 (8MB fp8)
  unsigned* scales = (unsigned*)ws;
  ushort_t* Wt = (ushort_t*)(ws + 256);
  ushort_t* P = (ushort_t*)(ws + 6291712);
  ushort_t* vpT = (ushort_t*)(ws + 73400576);
  unsigned char* qp8 = (unsigned char*)(ws + 90177792);
  unsigned char* kp8 = (unsigned char*)(ws + 98566400);

  hipMemsetAsync(scales, 0, 64, stream);
  absmax_k<<<dim3(64, 1, 3), 256, 0, stream>>>(Wq, Wk, Wv, scales);
  quant_w_k<<<dim3(32, 32, 3), 256, 0, stream>>>(Wq, Wk, Wv, scales, Wt);

  // Merged projections straight from f32 q/k/v (bm-fastest grid):
  // each z: M=8192, N=1024, K=1024. z<2 -> fp8 qp8/kp8; z==2 -> bf16 vpT.
  proj_f32a<<<dim3(64, 8, 3), 256, 0, stream>>>(q, k, v, Wt, vpT, qp8, bq, bk,
                                                bv);

  // logits = qp x kp^T / 32 via MX-fp8: M=N=2048, K=1024, batched over 4
  qk_fp8<<<dim3(16, 16, 4), 256, 0, stream>>>(qp8, kp8, P);

  softmax_k<<<8192, 256, 0, stream>>>(P);

  // out = P x vpT^T (bm-fastest): M=2048, N=1024, K=2048, fp32 store
  gemm_bt<2, 1><<<dim3(16, 8, 4), 256, 0, stream>>>(
      P, vpT, out, nullptr, nullptr, nullptr, nullptr, 2048, 1024, 1.0f,
      4194304L, 2097152L, 2097152L);
}

// Round 7
// 307.838 us; speedup vs baseline: 1.0418x; 1.0095x over previous
//
#include <hip/hip_runtime.h>
#include <stdint.h>

// B=4, S=2048, D_IN=D_MODEL=1024.
// Pipeline: absmax(W) -> quantize W^T bf16 ->
//   merged proj GEMM reads q/k/v f32 DIRECTLY (1-deep reg-staged A with
//   in-register f32->bf16 cvt; B via global_load_lds ONE TILE AHEAD into
//   double-buffered sB, drained at end-of-iter with a full compute phase of
//   slack; z<2 emits qp/kp fp8-e4m3, z==2 stores vp^T bf16)
//   -> QK^T via MX-scaled fp8 MFMA (K=128, scale=1) -> softmax(bf16) -> PV bf16.
// cast3_k eliminated: the proj GEMM has 83% HBM headroom -- f32 fetch is free.

typedef unsigned short ushort_t;
typedef __attribute__((ext_vector_type(8))) short short8;
typedef __bf16 bf16x8 __attribute__((ext_vector_type(8)));
typedef __attribute__((ext_vector_type(4))) float floatx4;
typedef __attribute__((ext_vector_type(8))) int int8v;

__device__ __forceinline__ ushort_t f2bf(float x) {
  unsigned u = __float_as_uint(x);
  unsigned r = (u + 0x7fffu + ((u >> 16) & 1u)) >> 16;  // RNE
  return (ushort_t)r;
}
__device__ __forceinline__ float bf2f(ushort_t u) {
  return __uint_as_float(((unsigned)u) << 16);
}
__device__ __forceinline__ unsigned char f2fp8(float x) {
  // v_cvt_pk_fp8_f32 (RNE, saturating), take low byte
  return (unsigned char)(__builtin_amdgcn_cvt_pk_fp8_f32(x, x, 0, false) & 0xff);
}
__device__ __forceinline__ int cvtpk_bf16(float a, float b) {
  // packed RNE f32->bf16: lo16 = cvt(a), hi16 = cvt(b)
  unsigned r;
  asm("v_cvt_pk_bf16_f32 %0, %1, %2" : "=v"(r) : "v"(a), "v"(b));
  return (int)r;
}

__device__ __forceinline__ void gl_lds16(const void* g, void* l) {
  __builtin_amdgcn_global_load_lds(
      (const __attribute__((address_space(1))) unsigned int*)g,
      (__attribute__((address_space(3))) unsigned int*)l, 16, 0, 0);
}

// ---------------------------------------------------------------------------
// Merged proj GEMM, 128x128 tile, BK=64, 4 waves. Minimal delta from the
// round-4-passed kernel: sB double-buffered, B staged ONE TILE AHEAD.
// Per-wave vmcnt ledger (generic iter t>=1, entry: 8 A(t) loads in flight):
//   STB(t+1)->+4glds(12); CVTWR waits vmcnt(4) (retires A(t), keeps glds);
//   LOAD_A(t+1)->+8(12); pre-compute wait = lgkmcnt(0) ONLY; barrier;
//   COMPUTE(buf t&1); end wait = lgkmcnt(0) vmcnt(8) (retires B(t+1) glds,
//   keeps A(t+1)); barrier.
// Iter 0 peeled (B(0)+B(1) both in flight): pre-compute wait vmcnt(12)
// retires B(0). Iter 15: no STB/LOAD_A; CVTWR's auto-wait drains A(15).
// B slack = full compute phase; A slack = full compute phase (L3-resident:
// FETCH=100MB == compulsory). WAR: all LDS writes sit >=1 barrier after the
// lgkmcnt(0)-drained reads of their buffer. Barrier count/positions = round-4.
// ---------------------------------------------------------------------------

#define SB0() __builtin_amdgcn_sched_barrier(0)

#define LOAD_A(dst, kt)                                                \
  {                                                                    \
    const long kb = (long)((kt) & 15) * 64;                            \
    _Pragma("unroll") for (int k = 0; k < 4; ++k) {                    \
      dst[2 * k] = *(const float4*)(gA + (long)k * 32 * 1024 + kb);    \
      dst[2 * k + 1] =                                                 \
          *(const float4*)(gA + (long)k * 32 * 1024 + kb + 4);         \
    }                                                                  \
  }
#define CVTWR(src)                                                     \
  {                                                                    \
    _Pragma("unroll") for (int k = 0; k < 4; ++k) {                    \
      int4 w;                                                          \
      w.x = cvtpk_bf16(src[2 * k].x, src[2 * k].y);                    \
      w.y = cvtpk_bf16(src[2 * k].z, src[2 * k].w);                    \
      w.z = cvtpk_bf16(src[2 * k + 1].x, src[2 * k + 1].y);            \
      w.w = cvtpk_bf16(src[2 * k + 1].z, src[2 * k + 1].w);            \
      *(int4*)&sA[awr[k]] = w;                                         \
    }                                                                  \
  }
#define STB(kt, buf)                                                   \
  {                                                                    \
    _Pragma("unroll") for (int i = 0; i < 4; ++i)                      \
        gl_lds16(gB + (long)i * 32 * 1024 + (long)((kt) & 15) * 64,    \
                 lB + (buf)*8192 + i * 2048);                          \
  }
#define COMPUTE(CB)                                                          \
  {                                                                          \
    _Pragma("unroll") for (int s = 0; s < 2; ++s) {                          \
      bf16x8 af[4], bfr[4];                                                  \
      _Pragma("unroll") for (int i = 0; i < 4; ++i) {                        \
        af[i] = *(const bf16x8*)&sA[offA[s][i]];                             \
        bfr[i] = *(const bf16x8*)&sB[(CB)*8192 + offB[s][i]];                \
      }                                                                      \
      _Pragma("unroll") for (int mi = 0; mi < 4; ++mi)                       \
          _Pragma("unroll") for (int ni = 0; ni < 4; ++ni) acc[mi][ni] =     \
              __builtin_amdgcn_mfma_f32_16x16x32_bf16(af[mi], bfr[ni],       \
                                                      acc[mi][ni], 0, 0, 0); \
    }                                                                        \
  }
#define PRE_BARRIER()                                   \
  {                                                     \
    asm volatile("s_waitcnt lgkmcnt(0)" ::: "memory");  \
    SB0();                                              \
    __builtin_amdgcn_s_barrier();                       \
    SB0();                                              \
  }
#define END_BARRIER()                                             \
  {                                                               \
    asm volatile("s_waitcnt lgkmcnt(0) vmcnt(8)" ::: "memory");   \
    SB0();                                                        \
    __builtin_amdgcn_s_barrier();                                 \
    SB0();                                                        \
  }
// iter t (1..14): compute tile t from sB[t&1]; stage B(t+1); load A(t+1)
#define ITER(t, AC, AN)          \
  {                              \
    STB((t) + 1, ((t) + 1) & 1); \
    CVTWR(AC);                   \
    SB0();                       \
    LOAD_A(AN, (t) + 1);         \
    SB0();                       \
    PRE_BARRIER();               \
    COMPUTE((t)&1);              \
    END_BARRIER();               \
  }

__global__ __launch_bounds__(256, 2) void proj_f32a(
    const float* __restrict__ Aq, const float* __restrict__ Ak,
    const float* __restrict__ Av, const ushort_t* __restrict__ Bt,
    void* __restrict__ Cv, void* __restrict__ Cv8,
    const float* __restrict__ bias0, const float* __restrict__ bias1,
    const float* __restrict__ bias2) {
  __shared__ __attribute__((aligned(16))) ushort_t sA[128 * 64];
  __shared__ __attribute__((aligned(16))) ushort_t sB[2 * 128 * 64];

  const int t = threadIdx.x;
  const int lane = t & 63;
  const int wave = t >> 6;
  const int bm = blockIdx.x;  // bm-fastest: bn-sharers of A land on same XCD
  const int bn = blockIdx.y;
  const int bz = blockIdx.z;

  const float* Ab = bz == 0 ? Aq : (bz == 1 ? Ak : Av);
  const ushort_t* Bb = Bt + (long)bz * 1048576L;

  const long a_row0 = (long)bm * 128;
  const long b_row0 = (long)bn * 128;

  // --- B staging via gl_lds: 32 rows x 8 chunks(16B)/issue, 4 issues ---
  const int crow = t >> 3;                  // 0..31
  const int schunk = (t & 7) ^ (crow & 7);  // pre-swizzled global chunk
  const ushort_t* gB = Bb + (b_row0 + crow) * 1024 + schunk * 8;
  ushort_t* lB = sB + wave * 512;  // + buf*8192 + issue*2048; HW adds lane*16B

  // --- A reg-staging: thread owns 8 f32 (one bf16 chunk) of 4 rows ---
  // ds_write target reproduces the gl_lds LDS image (same XOR swizzle).
  const int arow = t >> 3;  // 0..31
  const int achk = t & 7;
  const float* gA = Ab + (a_row0 + arow) * 1024 + achk * 8;
  int awr[4];
#pragma unroll
  for (int k = 0; k < 4; ++k)
    awr[k] = (k * 32 + arow) * 64 + ((achk ^ (arow & 7)) * 8);

  floatx4 acc[4][4];
#pragma unroll
  for (int i = 0; i < 4; ++i)
#pragma unroll
    for (int j = 0; j < 4; ++j) acc[i][j] = {0.f, 0.f, 0.f, 0.f};

  const int wm = (wave & 1) * 64;
  const int wn = (wave >> 1) * 64;
  const int fr = lane & 15;
  const int fg = lane >> 4;

  int offA[2][4], offB[2][4];
#pragma unroll
  for (int s = 0; s < 2; ++s)
#pragma unroll
    for (int i = 0; i < 4; ++i) {
      int rowA = wm + i * 16 + fr;
      int rowB = wn + i * 16 + fr;
      int cg = s * 4 + fg;
      offA[s][i] = rowA * 64 + ((cg ^ (rowA & 7)) * 8);
      offB[s][i] = rowB * 64 + ((cg ^ (rowB & 7)) * 8);
    }

  float4 aX[8], aY[8];

  // Prologue + peeled iter 0. Ledger: A(0)x8, B(0)x4, B(1)x4 = 16;
  // CVTWR waits vmcnt(8) (retires A(0)); +A(1)x8 = 16;
  // pre-compute vmcnt(12) retires B(0); end vmcnt(8) retires B(1).
  LOAD_A(aX, 0);
  STB(0, 0);
  STB(1, 1);
  CVTWR(aX);
  SB0();
  LOAD_A(aY, 1);
  SB0();
  asm volatile("s_waitcnt lgkmcnt(0) vmcnt(12)" ::: "memory");
  SB0();
  __builtin_amdgcn_s_barrier();
  SB0();
  COMPUTE(0);
  END_BARRIER();

  // iters 1..14 (7 unrolled pairs; parity keeps all indices static).
#pragma unroll 1
  for (int tp = 0; tp < 7; ++tp) {
    const int t1 = 2 * tp + 1;
    ITER(t1, aY, aX);      // odd t: consume A(t)=aY, load A(t+1)->aX
    ITER(t1 + 1, aX, aY);  // even t: consume aX, load ->aY
  }

  // iter 15: no staging; CVTWR's auto-wait drains A(15) (full-iter slack).
  CVTWR(aY);
  SB0();
  PRE_BARRIER();
  COMPUTE(1);

  // C/D layout: row=(lane>>4)*4+reg, col=lane&15  [m89/m91]
  const int r0 = fg * 4;
  const int cc = fr;
  const float* bias = bz == 0 ? bias0 : (bz == 1 ? bias1 : bias2);
  unsigned char* C8 = (unsigned char*)Cv8 + (long)bz * 8388608L;
  ushort_t* CvpT = (ushort_t*)Cv;

#pragma unroll
  for (int mi = 0; mi < 4; ++mi) {
#pragma unroll
    for (int ni = 0; ni < 4; ++ni) {
      long gm0 = a_row0 + wm + mi * 16 + r0;
      long gn = b_row0 + wn + ni * 16 + cc;
      float vv[4];
#pragma unroll
      for (int r = 0; r < 4; ++r) vv[r] = acc[mi][ni][r] + bias[gn];
      if (bz == 2) {
        // vp^T[b][gn][s]: r=0..3 contiguous in s; 8B packed store
        long b = gm0 >> 11, s = gm0 & 2047;
        ushort4 u4;
        u4.x = f2bf(vv[0]);
        u4.y = f2bf(vv[1]);
        u4.z = f2bf(vv[2]);
        u4.w = f2bf(vv[3]);
        *(ushort4*)&CvpT[b * (2048L * 1024L) + gn * 2048L + s] = u4;
      } else {
        // fp8 e4m3 store: qp8/kp8 [8192][1024] row-major
#pragma unroll
        for (int r = 0; r < 4; ++r) C8[(gm0 + r) * 1024 + gn] = f2fp8(vv[r]);
      }
    }
  }
}

#define BM 128
#define BN 128
#define BK 64

// CMODE: 2 = fp32 store Cz[gm*ldc+gn]  (PV GEMM)
// SWAP:  1 = bm from blockIdx.x (bm-fastest for XCD A-stripe sharing)
template <int CMODE, int SWAP>
__global__ __launch_bounds__(256, 2) void gemm_bt(
    const ushort_t* __restrict__ A, const ushort_t* __restrict__ Bt,
    void* __restrict__ Cv, void* __restrict__ Cv8,
    const float* __restrict__ bias0, const float* __restrict__ bias1,
    const float* __restrict__ bias2, int K, int ldc, float alpha, long strideA,
    long strideB, long strideC) {
  __shared__ __attribute__((aligned(16))) ushort_t sA[BM * BK];
  __shared__ __attribute__((aligned(16))) ushort_t sB[BN * BK];

  const int t = threadIdx.x;
  const int lane = t & 63;
  const int wave = t >> 6;
  const int bm = SWAP ? blockIdx.x : blockIdx.y;
  const int bn = SWAP ? blockIdx.y : blockIdx.x;
  const int bz = blockIdx.z;

  const ushort_t* Ab = A + (long)bz * strideA;
  const ushort_t* Bb = Bt + (long)bz * strideB;

  const long a_row0 = (long)bm * BM;
  const long b_row0 = (long)bn * BN;

  // Staging: 32 rows x 8 chunks(16B) per issue; 4 issues per matrix.
  // XOR swizzle: LDS[row][chunk] holds global[row][chunk ^ (row&7)].
  const int crow = t >> 3;                  // 0..31
  const int schunk = (t & 7) ^ (crow & 7);  // swizzled global chunk

  const ushort_t* gA = Ab + (a_row0 + crow) * (long)K + schunk * 8;
  const ushort_t* gB = Bb + (b_row0 + crow) * (long)K + schunk * 8;

  ushort_t* lA = sA + wave * 512;  // + issue*2048; HW adds lane*16B
  ushort_t* lB = sB + wave * 512;

  floatx4 acc[4][4];
#pragma unroll
  for (int i = 0; i < 4; ++i)
#pragma unroll
    for (int j = 0; j < 4; ++j) acc[i][j] = {0.f, 0.f, 0.f, 0.f};

  const int wm = (wave & 1) * 64;
  const int wn = (wave >> 1) * 64;
  const int fr = lane & 15;
  const int fg = lane >> 4;  // 0..3: which 16B chunk within a 32-k step

  int offA[2][4], offB[2][4];
#pragma unroll
  for (int s = 0; s < 2; ++s)
#pragma unroll
    for (int i = 0; i < 4; ++i) {
      int rowA = wm + i * 16 + fr;
      int rowB = wn + i * 16 + fr;
      int cg = s * 4 + fg;
      offA[s][i] = rowA * BK + ((cg ^ (rowA & 7)) * 8);
      offB[s][i] = rowB * BK + ((cg ^ (rowB & 7)) * 8);
    }

  for (int k0 = 0; k0 < K; k0 += BK) {
#pragma unroll
    for (int i = 0; i < 4; ++i) {
      gl_lds16(gA + (long)i * 32 * K, lA + i * 2048);
      gl_lds16(gB + (long)i * 32 * K, lB + i * 2048);
    }
    gA += BK;
    gB += BK;
    __syncthreads();  // staging complete

#pragma unroll
    for (int s = 0; s < 2; ++s) {
      bf16x8 af[4], bfr[4];
#pragma unroll
      for (int i = 0; i < 4; ++i) {
        af[i] = *(const bf16x8*)&sA[offA[s][i]];
        bfr[i] = *(const bf16x8*)&sB[offB[s][i]];
      }
#pragma unroll
      for (int mi = 0; mi < 4; ++mi)
#pragma unroll
        for (int ni = 0; ni < 4; ++ni)
          acc[mi][ni] = __builtin_amdgcn_mfma_f32_16x16x32_bf16(
              af[mi], bfr[ni], acc[mi][ni], 0, 0, 0);
    }
    __syncthreads();  // reads done before next stage overwrites
  }

  // C/D layout: row=(lane>>4)*4+reg, col=lane&15  [m89/m91]
  const int r0 = fg * 4;
  const int cc = fr;
  float* Cz32 = (float*)Cv + (long)bz * strideC;

#pragma unroll
  for (int mi = 0; mi < 4; ++mi) {
#pragma unroll
    for (int ni = 0; ni < 4; ++ni) {
      long gm0 = a_row0 + wm + mi * 16 + r0;
      long gn = b_row0 + wn + ni * 16 + cc;
      float vv[4];
#pragma unroll
      for (int r = 0; r < 4; ++r) vv[r] = acc[mi][ni][r] * alpha;
      if (CMODE == 2) {
#pragma unroll
        for (int r = 0; r < 4; ++r) Cz32[(gm0 + r) * ldc + gn] = vv[r];
      }
    }
  }
}

// QK^T with MX-scaled fp8 MFMA: K=128/instr, scale=2^0 (E8M0 127).
// A=qp8, B=kp8, both [4][2048][1024] fp8 e4m3; P bf16 [4][2048][2048], /32.
__global__ __launch_bounds__(256, 2) void qk_fp8(
    const unsigned char* __restrict__ Q8, const unsigned char* __restrict__ K8,
    ushort_t* __restrict__ P) {
  __shared__ __attribute__((aligned(16))) unsigned char sA[128 * 128];
  __shared__ __attribute__((aligned(16))) unsigned char sB[128 * 128];
  const int t = threadIdx.x;
  const int lane = t & 63, wave = t >> 6;
  const int bm = blockIdx.x, bn = blockIdx.y, bz = blockIdx.z;

  const unsigned char* Ab = Q8 + (long)bz * 2097152L + (long)bm * 128 * 1024;
  const unsigned char* Bb = K8 + (long)bz * 2097152L + (long)bn * 128 * 1024;

  // Staging: row = 128 B (BK=128 fp8). 256 thr x 16B = 32 rows/issue, 4 issues.
  const int crow = t >> 3;
  const int schunk = (t & 7) ^ (crow & 7);
  const unsigned char* gA = Ab + crow * 1024 + schunk * 16;
  const unsigned char* gB = Bb + crow * 1024 + schunk * 16;
  unsigned char* lA = sA + wave * 1024;  // + issue*4096; HW adds lane*16B
  unsigned char* lB = sB + wave * 1024;

  floatx4 acc[4][4];
#pragma unroll
  for (int i = 0; i < 4; ++i)
#pragma unroll
    for (int j = 0; j < 4; ++j) acc[i][j] = {0.f, 0.f, 0.f, 0.f};

  const int wm = (wave & 1) * 64;
  const int wn = (wave >> 1) * 64;
  const int fr = lane & 15;
  const int fg = lane >> 4;  // quad: k-bytes [fg*32, fg*32+32)

  int offA[4][2], offB[4][2];
#pragma unroll
  for (int i = 0; i < 4; ++i) {
    int rA = wm + i * 16 + fr;
    int rB = wn + i * 16 + fr;
    offA[i][0] = rA * 128 + (((2 * fg) ^ (rA & 7)) * 16);
    offA[i][1] = rA * 128 + (((2 * fg + 1) ^ (rA & 7)) * 16);
    offB[i][0] = rB * 128 + (((2 * fg) ^ (rB & 7)) * 16);
    offB[i][1] = rB * 128 + (((2 * fg + 1) ^ (rB & 7)) * 16);
  }

  for (int k0 = 0; k0 < 1024; k0 += 128) {
#pragma unroll
    for (int i = 0; i < 4; ++i) {
      gl_lds16(gA + (long)i * 32 * 1024, lA + i * 4096);
      gl_lds16(gB + (long)i * 32 * 1024, lB + i * 4096);
    }
    gA += 128;
    gB += 128;
    __syncthreads();

    int8v af[4], bfr[4];
#pragma unroll
    for (int i = 0; i < 4; ++i) {
      int4 lo = *(const int4*)&sA[offA[i][0]];
      int4 hi = *(const int4*)&sA[offA[i][1]];
      af[i][0] = lo.x; af[i][1] = lo.y; af[i][2] = lo.z; af[i][3] = lo.w;
      af[i][4] = hi.x; af[i][5] = hi.y; af[i][6] = hi.z; af[i][7] = hi.w;
      int4 lo2 = *(const int4*)&sB[offB[i][0]];
      int4 hi2 = *(const int4*)&sB[offB[i][1]];
      bfr[i][0] = lo2.x; bfr[i][1] = lo2.y; bfr[i][2] = lo2.z; bfr[i][3] = lo2.w;
      bfr[i][4] = hi2.x; bfr[i][5] = hi2.y; bfr[i][6] = hi2.z; bfr[i][7] = hi2.w;
    }
#pragma unroll
    for (int mi = 0; mi < 4; ++mi)
#pragma unroll
      for (int ni = 0; ni < 4; ++ni)
        acc[mi][ni] = __builtin_amdgcn_mfma_scale_f32_16x16x128_f8f6f4(
            af[mi], bfr[ni], acc[mi][ni], 0, 0, 0, 127, 0, 127);
    __syncthreads();
  }

  const int r0 = fg * 4;
  const int cc = fr;
#pragma unroll
  for (int mi = 0; mi < 4; ++mi)
#pragma unroll
    for (int ni = 0; ni < 4; ++ni)
#pragma unroll
      for (int r = 0; r < 4; ++r) {
        long gm = (long)bm * 128 + wm + mi * 16 + r0 + r;
        long gn = (long)bn * 128 + wn + ni * 16 + cc;
        P[(long)bz * 4194304L + gm * 2048 + gn] =
            f2bf(acc[mi][ni][r] * 0.03125f);
      }
}

__global__ __launch_bounds__(256) void absmax_k(
    const float* __restrict__ W0, const float* __restrict__ W1,
    const float* __restrict__ W2, unsigned* __restrict__ outv) {
  const float* W = blockIdx.z == 0 ? W0 : (blockIdx.z == 1 ? W1 : W2);
  float m = 0.f;
  const long n = 1024L * 1024L;
  for (long i = (long)blockIdx.x * blockDim.x + threadIdx.x; i < n;
       i += (long)gridDim.x * blockDim.x)
    m = fmaxf(m, fabsf(W[i]));
  for (int off = 32; off; off >>= 1) m = fmaxf(m, __shfl_xor(m, off));
  __shared__ float red[4];
  int lane = threadIdx.x & 63, wave = threadIdx.x >> 6;
  if (lane == 0) red[wave] = m;
  __syncthreads();
  if (threadIdx.x == 0) {
    m = fmaxf(fmaxf(red[0], red[1]), fmaxf(red[2], red[3]));
    atomicMax(&outv[blockIdx.z], __float_as_uint(m));  // positive: uint order
  }
}

__global__ __launch_bounds__(256) void quant_w_k(
    const float* __restrict__ W0, const float* __restrict__ W1,
    const float* __restrict__ W2, const unsigned* __restrict__ scales,
    ushort_t* __restrict__ Wt) {
  const int z = blockIdx.z;
  const float* W = z == 0 ? W0 : (z == 1 ? W1 : W2);
  const float s = __uint_as_float(scales[z]) * (1.0f / 128.0f);
  __shared__ float tile[32][33];
  const int tx = threadIdx.x & 31, ty = threadIdx.x >> 5;
  const int k0 = blockIdx.y * 32, n0 = blockIdx.x * 32;
#pragma unroll
  for (int i = 0; i < 4; ++i)
    tile[ty + i * 8][tx] = W[(long)(k0 + ty + i * 8) * 1024 + n0 + tx];
  __syncthreads();
  ushort_t* wt = Wt + (long)z * 1024 * 1024;
#pragma unroll
  for (int i = 0; i < 4; ++i) {
    float w = tile[tx][ty + i * 8];
    float qv = rintf(w / s) * s;  // rintf = RNE = jnp.round
    wt[(long)(n0 + ty + i * 8) * 1024 + k0 + tx] = f2bf(qv);
  }
}

__global__ __launch_bounds__(256) void softmax_k(ushort_t* __restrict__ P) {
  const long row = blockIdx.x;
  ushort_t* p = P + row * 2048;
  const int t = threadIdx.x;
  const int lane = t & 63, wave = t >> 6;
  short8 v8 = *(const short8*)&p[t * 8];
  float x[8];
#pragma unroll
  for (int j = 0; j < 8; ++j) x[j] = bf2f((ushort_t)v8[j]);
  float m = x[0];
#pragma unroll
  for (int j = 1; j < 8; ++j) m = fmaxf(m, x[j]);
  for (int off = 32; off; off >>= 1) m = fmaxf(m, __shfl_xor(m, off));
  __shared__ float rmax[4], rsum[4];
  if (lane == 0) rmax[wave] = m;
  __syncthreads();
  m = fmaxf(fmaxf(rmax[0], rmax[1]), fmaxf(rmax[2], rmax[3]));
  float s = 0.f;
#pragma unroll
  for (int j = 0; j < 8; ++j) {
    x[j] = __expf(x[j] - m);
    s += x[j];
  }
  for (int off = 32; off; off >>= 1) s += __shfl_xor(s, off);
  if (lane == 0) rsum[wave] = s;
  __syncthreads();
  s = rsum[0] + rsum[1] + rsum[2] + rsum[3];
  float inv = 1.0f / s;
  short8 o8;
#pragma unroll
  for (int j = 0; j < 8; ++j) o8[j] = (short)f2bf(x[j] * inv);
  *(short8*)&p[t * 8] = o8;
}

extern "C" void kernel_launch(void* const* d_in, const int* in_sizes, int n_in,
                              void* d_out, int out_size, void* d_ws,
                              size_t ws_size, hipStream_t stream) {
  const float* q = (const float*)d_in[0];
  const float* k = (const float*)d_in[1];
  const float* v = (const float*)d_in[2];
  const float* Wq = (const float*)d_in[3];
  const float* bq = (const float*)d_in[4];
  const float* Wk = (const float*)d_in[5];
  const float* bk = (const float*)d_in[6];
  const float* Wv = (const float*)d_in[7];
  const float* bv = (const float*)d_in[8];
  float* out = (float*)d_out;
  char* ws = (char*)d_ws;

  // Workspace layout (bytes). Total: 106,955,008 (unchanged, known ok).
  // scales @0 (256B); Wt @256 (6MB);
  // P @6,291,712 (64MB bf16 -> ends 73,400,576)
  // vpT @73,400,576 (16MB bf16)
  // qp8 @90,177,792 (8MB fp8); kp8 @98,566,400 (8MB fp8)
  unsigned* scales = (unsigned*)ws;
  ushort_t* Wt = (ushort_t*)(ws + 256);
  ushort_t* P = (ushort_t*)(ws + 6291712);
  ushort_t* vpT = (ushort_t*)(ws + 73400576);
  unsigned char* qp8 = (unsigned char*)(ws + 90177792);
  unsigned char* kp8 = (unsigned char*)(ws + 98566400);

  hipMemsetAsync(scales, 0, 64, stream);
  absmax_k<<<dim3(64, 1, 3), 256, 0, stream>>>(Wq, Wk, Wv, scales);
  quant_w_k<<<dim3(32, 32, 3), 256, 0, stream>>>(Wq, Wk, Wv, scales, Wt);

  // Merged projections straight from f32 q/k/v (bm-fastest grid):
  // each z: M=8192, N=1024, K=1024. z<2 -> fp8 qp8/kp8; z==2 -> bf16 vpT.
  proj_f32a<<<dim3(64, 8, 3), 256, 0, stream>>>(q, k, v, Wt, vpT, qp8, bq, bk,
                                                bv);

  // logits = qp x kp^T / 32 via MX-fp8: M=N=2048, K=1024, batched over 4
  qk_fp8<<<dim3(16, 16, 4), 256, 0, stream>>>(qp8, kp8, P);

  softmax_k<<<8192, 256, 0, stream>>>(P);

  // out = P x vpT^T (bm-fastest): M=2048, N=1024, K=2048, fp32 store
  gemm_bt<2, 1><<<dim3(16, 8, 4), 256, 0, stream>>>(
      P, vpT, out, nullptr, nullptr, nullptr, nullptr, 2048, 1024, 1.0f,
      4194304L, 2097152L, 2097152L);
}